// Round 2
// baseline (355.444 us; speedup 1.0000x reference)
//
#include <hip/hip_runtime.h>
#include <stdint.h>

// ScoreMatching: B=2048, D=64, H=512.
// out[b] = 0.5*||s_b||^2 + tr(W4 M3 W3 M2 W2 M1 W1)_b
// div_b = sum_{i,d} m2[i] * C[i,d] * G[i,d]
//   C = W2 @ (M1 .* W1)      [512 x 64]   A-frag = W2 rows,  B-frag = masked W1T rows
//   G = W3^T @ (M3 .* W4^T)  [512 x 64]   A-frag = W3T rows, B-frag = masked W4 rows
// R6 changes:
//  - div v2: fragments are sample-independent (masks applied in regs), so share
//    them: block = 4 waves = 4 samples x ONE 64-row tile; per kc the block
//    stages 16 raw fragments (16KB) into double-buffered LDS via
//    global_load_lds (prefetch distance = 1 full kc), waves ds_read_b128 them.
//    Global traffic ~4GB -> ~1GB; load latency hidden under MFMA phase.
//    One __syncthreads per kc; 32KB LDS -> 2 blocks/CU so barriers overlap.
//  - forward: 1024 thr/block (4 waves/SIMD, was 2), thread = 2 units x 2
//    samples. Latency-bound -> double TLP.

typedef __attribute__((ext_vector_type(8))) short short8;
typedef __attribute__((ext_vector_type(4))) float f32x4;

union U16x8 {
  uint4 u;
  short8 s;
};

__device__ __forceinline__ uint16_t f2bf(float f) {
  uint32_t u = __float_as_uint(f);
  uint32_t lsb = (u >> 16) & 1u;
  u += 0x7FFFu + lsb;  // round-to-nearest-even
  return (uint16_t)(u >> 16);
}

// async global->LDS, 16B per lane: lane's data lands at lds_base + lane*16.
__device__ __forceinline__ void lds_load16(const uint4* gsrc, uint4* ldst) {
  __builtin_amdgcn_global_load_lds(
      (const __attribute__((address_space(1))) void*)gsrc,
      (__attribute__((address_space(3))) void*)ldst, 16, 0, 0);
}

// ---------------- convert: build swizzled bf16 fragments + fp32 transposes ----------------
// Fragment order (16x16x32 bf16 MFMA): lane = quad*16 + l15 holds 8 contiguous
// bf16 = 16 B; A-frag element (m=l15, k=quad*8+j); B-frag (n=l15, k=quad*8+j).
// A2swz[((r16*16 + kc)*64 + lane)*8 + j] = W2 [r16*16+l15][kc*32+quad*8+j]
// A3swz[  same index                   ] = W3T[r16*16+l15][kc*32+quad*8+j]
// B1swz[((kc*4 + jt)*64 + lane)*8 + j]  = W1T[jt*16+l15 ][kc*32+quad*8+j]
// B4swz[  same index                 ]  = W4 [jt*16+l15 ][kc*32+quad*8+j]
__global__ __launch_bounds__(256) void convert_kernel(
    const float* __restrict__ W1, const float* __restrict__ W2,
    const float* __restrict__ W3, const float* __restrict__ W4,
    uint16_t* __restrict__ A2swz, uint16_t* __restrict__ A3swz,
    uint16_t* __restrict__ B1swz, uint16_t* __restrict__ B4swz,
    float* __restrict__ W2Tf, float* __restrict__ W3Tf,
    float* __restrict__ W1Tf, float* __restrict__ W4Tf) {
  const int i = blockIdx.x * 256 + threadIdx.x;
  if (i < 262144) {  // A2swz
    const int e = i;
    const int f = e >> 3, j = e & 7;
    const int lane = f & 63, fk = f >> 6;
    const int kc = fk & 15, r16 = fk >> 4;
    const int l15 = lane & 15, quad = lane >> 4;
    const int row = r16 * 16 + l15, col = kc * 32 + quad * 8 + j;
    A2swz[e] = f2bf(W2[row * 512 + col]);
  } else if (i < 524288) {  // A3swz (= W3 transposed)
    const int e = i - 262144;
    const int f = e >> 3, j = e & 7;
    const int lane = f & 63, fk = f >> 6;
    const int kc = fk & 15, r16 = fk >> 4;
    const int l15 = lane & 15, quad = lane >> 4;
    const int row = r16 * 16 + l15, col = kc * 32 + quad * 8 + j;
    A3swz[e] = f2bf(W3[col * 512 + row]);
  } else if (i < 557056) {  // B1swz (= W1 transposed)
    const int e = i - 524288;
    const int f = e >> 3, j = e & 7;
    const int lane = f & 63, fk = f >> 6;
    const int kc = fk >> 2, jt = fk & 3;
    const int l15 = lane & 15, quad = lane >> 4;
    const int d = jt * 16 + l15, col = kc * 32 + quad * 8 + j;
    B1swz[e] = f2bf(W1[col * 64 + d]);
  } else if (i < 589824) {  // B4swz (= W4 row-major)
    const int e = i - 557056;
    const int f = e >> 3, j = e & 7;
    const int lane = f & 63, fk = f >> 6;
    const int kc = fk >> 2, jt = fk & 3;
    const int l15 = lane & 15, quad = lane >> 4;
    const int d = jt * 16 + l15, col = kc * 32 + quad * 8 + j;
    B4swz[e] = f2bf(W4[d * 512 + col]);
  } else if (i < 851968) {  // W2Tf [k][j]
    const int e = i - 589824;
    const int k = e >> 9, jj = e & 511;
    W2Tf[e] = W2[jj * 512 + k];
  } else if (i < 1114112) {  // W3Tf [k][j]
    const int e = i - 851968;
    const int k = e >> 9, jj = e & 511;
    W3Tf[e] = W3[jj * 512 + k];
  } else if (i < 1146880) {  // W1Tf [k][j], k<64
    const int e = i - 1114112;
    const int k = e >> 9, jj = e & 511;
    W1Tf[e] = W1[jj * 64 + k];
  } else if (i < 1179648) {  // W4Tf [k][d]
    const int e = i - 1146880;
    const int k = e >> 6, d = e & 63;
    W4Tf[e] = W4[d * 512 + k];
  }
}

// ---------------- forward (fp32): packed masks + 0.5*||s||^2 ----------------
// 1024 threads = 16 waves (4/SIMD), 8 samples/block, 256 blocks.
// Thread: sh = t>>8 (sample pair: samples sh*2, sh*2+1), jq2 = t&255 -> units
// j2, j2+1. Per k: one broadcast LDS float2 (2 samples) + one coalesced global
// float2 (2 units, 8B/lane) -> 4 FMA.
// Masks: 2 bits per (thread, sample) -> LDS atomicOr into u32 words; bit u of
// word w = unit w*32+u  (matches div kernel's m?p layout).
__device__ __forceinline__ void fwd_hidden(
    const float* __restrict__ WT, const float* __restrict__ bias,
    const float2* __restrict__ src,  // pre-offset to this thread's float2 half
    float2* __restrict__ dst,        // pre-offset likewise; stride 2 float2/elt
    uint32_t* __restrict__ mw, uint32_t* __restrict__ mglob,
    int sh, int jq2, int t, int K) {
  const int j2 = jq2 * 2;
  float a[2][2];
  {
    const float2 bb = *(const float2*)(bias + j2);
    a[0][0] = bb.x; a[0][1] = bb.x;
    a[1][0] = bb.y; a[1][1] = bb.y;
  }
#pragma unroll 8
  for (int k = 0; k < K; ++k) {
    const float2 w = *(const float2*)(WT + (size_t)k * 512 + j2);
    const float2 h = src[k * 2];
    a[0][0] = fmaf(w.x, h.x, a[0][0]); a[0][1] = fmaf(w.x, h.y, a[0][1]);
    a[1][0] = fmaf(w.y, h.x, a[1][0]); a[1][1] = fmaf(w.y, h.y, a[1][1]);
  }
  const int word = jq2 >> 4, shift = 2 * (jq2 & 15);
#pragma unroll
  for (int si = 0; si < 2; ++si) {
    uint32_t nib = (a[0][si] > 0.f ? 1u : 0u) | (a[1][si] > 0.f ? 2u : 0u);
    if (nib) atomicOr(&mw[(sh * 2 + si) * 16 + word], nib << shift);
  }
#pragma unroll
  for (int u = 0; u < 2; ++u) {
    float2 r;
    r.x = a[u][0] > 0.f ? a[u][0] : 0.f;
    r.y = a[u][1] > 0.f ? a[u][1] : 0.f;
    dst[(j2 + u) * 2] = r;
  }
  __syncthreads();
  if (t < 128) {
    mglob[(size_t)(t >> 4) * 16 + (t & 15)] = mw[t];
    mw[t] = 0;
  }
  __syncthreads();
}

__global__ __launch_bounds__(1024) void forward_kernel(
    const float* __restrict__ x,
    const float* __restrict__ W1Tf, const float* __restrict__ b1,
    const float* __restrict__ W2Tf, const float* __restrict__ b2,
    const float* __restrict__ W3Tf, const float* __restrict__ b3,
    const float* __restrict__ W4Tf, const float* __restrict__ b4,
    uint32_t* __restrict__ m1p, uint32_t* __restrict__ m2p,
    uint32_t* __restrict__ m3p, float* __restrict__ out) {
  __shared__ float4 xs[2][64];      // [grp][k] : 4 samples per grp
  __shared__ float4 hp[2][2][512];  // [buf][grp][k]
  __shared__ uint32_t mw[128];      // [sample][16 words]
  const int t = threadIdx.x;
  const int b0 = blockIdx.x * 8;
  const int sh = t >> 8;    // 0..3: sample pair (samples sh*2, sh*2+1)
  const int jq2 = t & 255;  // unit pair
  const int g = sh >> 1;    // float4 group (4 samples)
  const int half = sh & 1;  // float2 half within the group

  if (t < 512) {
    const int k = t >> 3, s = t & 7;  // covers 8 samples x 64 k
    ((float*)&xs[s >> 2][k])[s & 3] = x[(size_t)(b0 + s) * 64 + k];
  }
  if (t < 128) mw[t] = 0;
  __syncthreads();

  fwd_hidden(W1Tf, b1, (const float2*)&xs[g][0] + half,
             (float2*)&hp[0][g][0] + half, mw, m1p + (size_t)b0 * 16, sh, jq2, t, 64);
  fwd_hidden(W2Tf, b2, (const float2*)&hp[0][g][0] + half,
             (float2*)&hp[1][g][0] + half, mw, m2p + (size_t)b0 * 16, sh, jq2, t, 512);
  fwd_hidden(W3Tf, b3, (const float2*)&hp[1][g][0] + half,
             (float2*)&hp[0][g][0] + half, mw, m3p + (size_t)b0 * 16, sh, jq2, t, 512);

  // ---- layer 4 (K=512, D=64) + 0.5*||s||^2 : wave wv (<8) -> sample wv ----
  {
    const int wv = t >> 6, lane = t & 63;
    if (wv < 8) {
      const int s = wv;
      const float* h = (const float*)&hp[0][s >> 2][0] + (s & 3);
      float acc = b4[lane];
#pragma unroll 8
      for (int k = 0; k < 512; ++k)
        acc = fmaf(W4Tf[k * 64 + lane], h[k * 4], acc);
      float sq = acc * acc;
#pragma unroll
      for (int off = 32; off; off >>= 1) sq += __shfl_down(sq, off, 64);
      if (lane == 0) out[b0 + s] = 0.5f * sq;
    }
  }
}

// ---------------- divergence v2: LDS-staged fragment sharing ----------------
// grid (512 sample-quads, 8 row-tiles of 64); block 256 = 4 waves.
// Wave wv -> sample g4*4+wv, rows blockIdx.y*64..+64, cols 0..64 (acc 128 AGPR).
// Per kc the block stages 16 raw fragments (slots: A2 it0-3 | A3 it0-3 |
// B1 jt0-3 | B4 jt0-3; 1KB each) into LDS buf^1 via global_load_lds (wave wv
// stages slots wv*4..wv*4+3), computes from buf, then one __syncthreads
// (drains vmcnt -> staging complete, reads done). Prefetch distance = 1 kc.
__device__ __forceinline__ void expand_mask(uint32_t byte8, uint32_t mk[4]) {
#pragma unroll
  for (int i = 0; i < 4; ++i) {
    mk[i] = (((byte8 >> (2 * i)) & 1u) ? 0x0000FFFFu : 0u) |
            (((byte8 >> (2 * i + 1)) & 1u) ? 0xFFFF0000u : 0u);
  }
}

__global__ __launch_bounds__(256, 2) void div_kernel(
    const uint4* __restrict__ A2swz, const uint4* __restrict__ A3swz,
    const uint4* __restrict__ B1swz, const uint4* __restrict__ B4swz,
    const uint32_t* __restrict__ m1p, const uint32_t* __restrict__ m2p,
    const uint32_t* __restrict__ m3p, float* __restrict__ out) {
  __shared__ uint4 sfrag[2][16][64];  // 32KB: [buf][slot][lane]
  const int t = threadIdx.x;
  const int lane = t & 63, wv = t >> 6;
  const int l15 = lane & 15, quad = lane >> 4;
  (void)l15;
  const int g4 = blockIdx.x;
  const int rowB0 = blockIdx.y * 64;
  const int b = g4 * 4 + wv;          // this wave's sample
  const int r16b = blockIdx.y * 4;    // row-16-tile base

  // staging source base for this wave's 4 slots
  const uint4* sb = (wv == 0) ? A2swz : (wv == 1) ? A3swz : (wv == 2) ? B1swz : B4swz;

  f32x4 accC[4][4], accG[4][4];
#pragma unroll
  for (int it = 0; it < 4; ++it)
#pragma unroll
    for (int jt = 0; jt < 4; ++jt) {
      accC[it][jt] = (f32x4){0.f, 0.f, 0.f, 0.f};
      accG[it][jt] = (f32x4){0.f, 0.f, 0.f, 0.f};
    }

  const uint32_t* m1w = m1p + (size_t)b * 16;
  const uint32_t* m3w = m3p + (size_t)b * 16;

  // stage(buf, kc): wave wv stages its 4 slots
  auto stage = [&](int sbuf, int kc) {
#pragma unroll
    for (int q = 0; q < 4; ++q) {
      const size_t off = (wv < 2)
          ? ((size_t)((r16b + q) * 16 + kc) * 64 + lane)   // A2 / A3
          : ((size_t)(kc * 4 + q) * 64 + lane);            // B1 / B4
      lds_load16(sb + off, &sfrag[sbuf][wv * 4 + q][0]);
    }
  };

  stage(0, 0);
  __syncthreads();  // drains vmcnt(0): buf0 staged

  int buf = 0;
#pragma unroll 1
  for (int kc = 0; kc < 16; ++kc) {
    if (kc < 15) stage(buf ^ 1, kc + 1);  // prefetch next kc under compute

    uint4 a2[4], a3[4], u1[4], u4[4];
#pragma unroll
    for (int q = 0; q < 4; ++q) {
      a2[q] = sfrag[buf][q][lane];
      a3[q] = sfrag[buf][4 + q][lane];
      u1[q] = sfrag[buf][8 + q][lane];
      u4[q] = sfrag[buf][12 + q][lane];
    }

    const uint32_t m1d = __builtin_amdgcn_readfirstlane(m1w[kc]);
    const uint32_t m3d = __builtin_amdgcn_readfirstlane(m3w[kc]);
    uint32_t mk1[4], mk3[4];
    expand_mask((m1d >> (quad * 8)) & 0xFFu, mk1);
    expand_mask((m3d >> (quad * 8)) & 0xFFu, mk3);

    short8 bC[4];
#pragma unroll
    for (int jt = 0; jt < 4; ++jt) {
      U16x8 u;
      u.u = u1[jt];
      u.u.x &= mk1[0]; u.u.y &= mk1[1]; u.u.z &= mk1[2]; u.u.w &= mk1[3];
      bC[jt] = u.s;
    }
#pragma unroll
    for (int it = 0; it < 4; ++it) {
      U16x8 ua;
      ua.u = a2[it];
      const short8 af = ua.s;
#pragma unroll
      for (int jt = 0; jt < 4; ++jt)
        accC[it][jt] = __builtin_amdgcn_mfma_f32_16x16x32_bf16(af, bC[jt], accC[it][jt], 0, 0, 0);
    }
    short8 bG[4];
#pragma unroll
    for (int jt = 0; jt < 4; ++jt) {
      U16x8 u;
      u.u = u4[jt];
      u.u.x &= mk3[0]; u.u.y &= mk3[1]; u.u.z &= mk3[2]; u.u.w &= mk3[3];
      bG[jt] = u.s;
    }
#pragma unroll
    for (int it = 0; it < 4; ++it) {
      U16x8 ua;
      ua.u = a3[it];
      const short8 af = ua.s;
#pragma unroll
      for (int jt = 0; jt < 4; ++jt)
        accG[it][jt] = __builtin_amdgcn_mfma_f32_16x16x32_bf16(af, bG[jt], accG[it][jt], 0, 0, 0);
    }
    __syncthreads();  // staging of buf^1 complete + all reads of buf done
    buf ^= 1;
  }

  // epilogue: dsum = sum m2[row] * C .* G ; C/D layout: row = quad*4+reg, col = l15
  const uint32_t* m2w = m2p + (size_t)b * 16;
  float dsum = 0.f;
#pragma unroll
  for (int it = 0; it < 4; ++it) {
    const int rloc = it * 16 + quad * 4;
    const uint32_t md = m2w[(rowB0 + rloc) >> 5];
    const uint32_t bits = (md >> (rloc & 31)) & 0xFu;
    const float w0 = (bits & 1u) ? 1.f : 0.f;
    const float w1 = (bits & 2u) ? 1.f : 0.f;
    const float w2 = (bits & 4u) ? 1.f : 0.f;
    const float w3 = (bits & 8u) ? 1.f : 0.f;
#pragma unroll
    for (int jt = 0; jt < 4; ++jt) {
      dsum = fmaf(w0, accC[it][jt][0] * accG[it][jt][0], dsum);
      dsum = fmaf(w1, accC[it][jt][1] * accG[it][jt][1], dsum);
      dsum = fmaf(w2, accC[it][jt][2] * accG[it][jt][2], dsum);
      dsum = fmaf(w3, accC[it][jt][3] * accG[it][jt][3], dsum);
    }
  }
#pragma unroll
  for (int off = 32; off; off >>= 1) dsum += __shfl_down(dsum, off, 64);
  if (lane == 0) atomicAdd(out + b, dsum);
}

extern "C" void kernel_launch(void* const* d_in, const int* in_sizes, int n_in,
                              void* d_out, int out_size, void* d_ws, size_t ws_size,
                              hipStream_t stream) {
  const float* x  = (const float*)d_in[0];
  const float* W1 = (const float*)d_in[1];
  const float* b1 = (const float*)d_in[2];
  const float* W2 = (const float*)d_in[3];
  const float* b2 = (const float*)d_in[4];
  const float* W3 = (const float*)d_in[5];
  const float* b3 = (const float*)d_in[6];
  const float* W4 = (const float*)d_in[7];
  const float* b4 = (const float*)d_in[8];
  float* out = (float*)d_out;

  // workspace layout (bytes), total 3,932,160:
  char* ws = (char*)d_ws;
  uint16_t* A2swz = (uint16_t*)(ws + 0);        // 524288
  uint16_t* A3swz = (uint16_t*)(ws + 524288);   // 524288
  uint16_t* B1swz = (uint16_t*)(ws + 1048576);  // 65536
  uint16_t* B4swz = (uint16_t*)(ws + 1114112);  // 65536
  float*    W2Tf  = (float*)(ws + 1179648);     // 1048576
  float*    W3Tf  = (float*)(ws + 2228224);     // 1048576
  float*    W1Tf  = (float*)(ws + 3276800);     // 131072
  float*    W4Tf  = (float*)(ws + 3407872);     // 131072
  uint32_t* m1p   = (uint32_t*)(ws + 3538944);  // 131072 (2048 x 512 bits)
  uint32_t* m2p   = (uint32_t*)(ws + 3670016);  // 131072
  uint32_t* m3p   = (uint32_t*)(ws + 3801088);  // 131072
  if (ws_size < 3932160) return;

  convert_kernel<<<4608, 256, 0, stream>>>(W1, W2, W3, W4,
                                           A2swz, A3swz, B1swz, B4swz,
                                           W2Tf, W3Tf, W1Tf, W4Tf);
  forward_kernel<<<256, 1024, 0, stream>>>(x, W1Tf, b1, W2Tf, b2, W3Tf, b3,
                                           W4Tf, b4, m1p, m2p, m3p, out);
  div_kernel<<<dim3(512, 8), 256, 0, stream>>>((const uint4*)A2swz,
                                               (const uint4*)A3swz,
                                               (const uint4*)B1swz,
                                               (const uint4*)B4swz,
                                               m1p, m2p, m3p, out);
}

// Round 3
// 303.525 us; speedup vs baseline: 1.1711x; 1.1711x over previous
//
#include <hip/hip_runtime.h>
#include <stdint.h>

// ScoreMatching: B=2048, D=64, H=512.
// out[b] = 0.5*||s_b||^2 + tr(W4 M3 W3 M2 W2 M1 W1)_b
// div_b = sum_{i,d} m2[i] * C[i,d] * G[i,d]
//   C = W2 @ (M1 .* W1)      [512 x 64]   A-frag = W2 rows,  B-frag = masked W1T rows
//   G = W3^T @ (M3 .* W4^T)  [512 x 64]   A-frag = W3T rows, B-frag = masked W4 rows
// R7 changes:
//  - forward v3: thread = 1 hidden unit x 8 samples. Per k: ONE coalesced 4B
//    W-load (block reads each weight matrix exactly once: was 4 duplicate
//    128-thread j-groups re-streaming 1MB from L2), 2 broadcast ds_read_b128
//    of h[k][*] (uniform address), 8 indep FMA chains. ReLU masks via __ballot
//    (wave w = units w*64..w*64+63 = mask words 2w,2w+1) -> no atomics.
//  - div: unchanged structure (R0==R2 at 164us proved it's not load-path
//    bound); per-kc scalar mask loads software-pipelined 1 kc ahead so their
//    ~200cyc L2 latency stops blocking the B-fragment MFMAs.

typedef __attribute__((ext_vector_type(8))) short short8;
typedef __attribute__((ext_vector_type(4))) float f32x4;

union U16x8 {
  uint4 u;
  short8 s;
};

__device__ __forceinline__ uint16_t f2bf(float f) {
  uint32_t u = __float_as_uint(f);
  uint32_t lsb = (u >> 16) & 1u;
  u += 0x7FFFu + lsb;  // round-to-nearest-even
  return (uint16_t)(u >> 16);
}

// async global->LDS, 16B per lane: lane's data lands at lds_base + lane*16.
__device__ __forceinline__ void lds_load16(const uint4* gsrc, uint4* ldst) {
  __builtin_amdgcn_global_load_lds(
      (const __attribute__((address_space(1))) void*)gsrc,
      (__attribute__((address_space(3))) void*)ldst, 16, 0, 0);
}

// ---------------- convert: build swizzled bf16 fragments + fp32 transposes ----------------
// Fragment order (16x16x32 bf16 MFMA): lane = quad*16 + l15 holds 8 contiguous
// bf16 = 16 B; A-frag element (m=l15, k=quad*8+j); B-frag (n=l15, k=quad*8+j).
// A2swz[((r16*16 + kc)*64 + lane)*8 + j] = W2 [r16*16+l15][kc*32+quad*8+j]
// A3swz[  same index                   ] = W3T[r16*16+l15][kc*32+quad*8+j]
// B1swz[((kc*4 + jt)*64 + lane)*8 + j]  = W1T[jt*16+l15 ][kc*32+quad*8+j]
// B4swz[  same index                 ]  = W4 [jt*16+l15 ][kc*32+quad*8+j]
__global__ __launch_bounds__(256) void convert_kernel(
    const float* __restrict__ W1, const float* __restrict__ W2,
    const float* __restrict__ W3, const float* __restrict__ W4,
    uint16_t* __restrict__ A2swz, uint16_t* __restrict__ A3swz,
    uint16_t* __restrict__ B1swz, uint16_t* __restrict__ B4swz,
    float* __restrict__ W2Tf, float* __restrict__ W3Tf,
    float* __restrict__ W1Tf, float* __restrict__ W4Tf) {
  const int i = blockIdx.x * 256 + threadIdx.x;
  if (i < 262144) {  // A2swz
    const int e = i;
    const int f = e >> 3, j = e & 7;
    const int lane = f & 63, fk = f >> 6;
    const int kc = fk & 15, r16 = fk >> 4;
    const int l15 = lane & 15, quad = lane >> 4;
    const int row = r16 * 16 + l15, col = kc * 32 + quad * 8 + j;
    A2swz[e] = f2bf(W2[row * 512 + col]);
  } else if (i < 524288) {  // A3swz (= W3 transposed)
    const int e = i - 262144;
    const int f = e >> 3, j = e & 7;
    const int lane = f & 63, fk = f >> 6;
    const int kc = fk & 15, r16 = fk >> 4;
    const int l15 = lane & 15, quad = lane >> 4;
    const int row = r16 * 16 + l15, col = kc * 32 + quad * 8 + j;
    A3swz[e] = f2bf(W3[col * 512 + row]);
  } else if (i < 557056) {  // B1swz (= W1 transposed)
    const int e = i - 524288;
    const int f = e >> 3, j = e & 7;
    const int lane = f & 63, fk = f >> 6;
    const int kc = fk >> 2, jt = fk & 3;
    const int l15 = lane & 15, quad = lane >> 4;
    const int d = jt * 16 + l15, col = kc * 32 + quad * 8 + j;
    B1swz[e] = f2bf(W1[col * 64 + d]);
  } else if (i < 589824) {  // B4swz (= W4 row-major)
    const int e = i - 557056;
    const int f = e >> 3, j = e & 7;
    const int lane = f & 63, fk = f >> 6;
    const int kc = fk >> 2, jt = fk & 3;
    const int l15 = lane & 15, quad = lane >> 4;
    const int d = jt * 16 + l15, col = kc * 32 + quad * 8 + j;
    B4swz[e] = f2bf(W4[d * 512 + col]);
  } else if (i < 851968) {  // W2Tf [k][j]
    const int e = i - 589824;
    const int k = e >> 9, jj = e & 511;
    W2Tf[e] = W2[jj * 512 + k];
  } else if (i < 1114112) {  // W3Tf [k][j]
    const int e = i - 851968;
    const int k = e >> 9, jj = e & 511;
    W3Tf[e] = W3[jj * 512 + k];
  } else if (i < 1146880) {  // W1Tf [k][j], k<64
    const int e = i - 1114112;
    const int k = e >> 9, jj = e & 511;
    W1Tf[e] = W1[jj * 64 + k];
  } else if (i < 1179648) {  // W4Tf [k][d]
    const int e = i - 1146880;
    const int k = e >> 6, d = e & 63;
    W4Tf[e] = W4[d * 512 + k];
  }
}

// ---------------- forward v3 (fp32): ballot masks, unit-per-thread ----------------
// 512 threads = 8 waves (2/SIMD), 8 samples/block, 256 blocks (1/CU).
// Hidden layers: thread t owns unit j=t for all 8 samples. Per k: one coalesced
// 4B W-load + two broadcast ds_read_b128 (h[k][0..3], h[k][4..7]) + 8 FMA.
// Mask: wave w covers units w*64..w*64+63 -> __ballot(a>0) = words 2w, 2w+1 of
// the packed mask (bit u of word W = unit W*32+u), stored by lane 0. No atomics.
__device__ __forceinline__ void relu_store_mask(
    float acc[8], float4 (*hdst)[2], uint32_t* __restrict__ mbase,
    int t, int lane, int wv) {
#pragma unroll
  for (int s = 0; s < 8; ++s) {
    const unsigned long long bal = __ballot(acc[s] > 0.f);
    if (lane == 0) {
      uint2 w2;
      w2.x = (uint32_t)bal;
      w2.y = (uint32_t)(bal >> 32);
      *(uint2*)(mbase + (size_t)s * 16 + 2 * wv) = w2;
    }
  }
  float4 r0, r1;
  r0.x = acc[0] > 0.f ? acc[0] : 0.f;
  r0.y = acc[1] > 0.f ? acc[1] : 0.f;
  r0.z = acc[2] > 0.f ? acc[2] : 0.f;
  r0.w = acc[3] > 0.f ? acc[3] : 0.f;
  r1.x = acc[4] > 0.f ? acc[4] : 0.f;
  r1.y = acc[5] > 0.f ? acc[5] : 0.f;
  r1.z = acc[6] > 0.f ? acc[6] : 0.f;
  r1.w = acc[7] > 0.f ? acc[7] : 0.f;
  hdst[t][0] = r0;
  hdst[t][1] = r1;
}

__global__ __launch_bounds__(512) void forward_kernel(
    const float* __restrict__ x,
    const float* __restrict__ W1Tf, const float* __restrict__ b1,
    const float* __restrict__ W2Tf, const float* __restrict__ b2,
    const float* __restrict__ W3Tf, const float* __restrict__ b3,
    const float* __restrict__ W4Tf, const float* __restrict__ b4,
    uint32_t* __restrict__ m1p, uint32_t* __restrict__ m2p,
    uint32_t* __restrict__ m3p, float* __restrict__ out) {
  __shared__ float4 xs[64][2];   // [k][half] : 8 samples
  __shared__ float4 hA[512][2];  // [unit][half]
  __shared__ float4 hB[512][2];
  const int t = threadIdx.x;
  const int lane = t & 63, wv = t >> 6;
  const int b0 = blockIdx.x * 8;

  {
    const int k = t >> 3, s = t & 7;  // 512 threads cover 8 samples x 64 k
    ((float*)&xs[k][0])[s] = x[(size_t)(b0 + s) * 64 + k];
  }
  __syncthreads();

  float acc[8];

  // ---- layer 1: K=64 ----
  {
    const float bj = b1[t];
#pragma unroll
    for (int s = 0; s < 8; ++s) acc[s] = bj;
#pragma unroll 8
    for (int k = 0; k < 64; ++k) {
      const float w = W1Tf[(size_t)k * 512 + t];
      const float4 h0 = xs[k][0], h1 = xs[k][1];
      acc[0] = fmaf(w, h0.x, acc[0]); acc[1] = fmaf(w, h0.y, acc[1]);
      acc[2] = fmaf(w, h0.z, acc[2]); acc[3] = fmaf(w, h0.w, acc[3]);
      acc[4] = fmaf(w, h1.x, acc[4]); acc[5] = fmaf(w, h1.y, acc[5]);
      acc[6] = fmaf(w, h1.z, acc[6]); acc[7] = fmaf(w, h1.w, acc[7]);
    }
    relu_store_mask(acc, hA, m1p + (size_t)b0 * 16, t, lane, wv);
  }
  __syncthreads();

  // ---- layer 2: K=512, hA -> hB ----
  {
    const float bj = b2[t];
#pragma unroll
    for (int s = 0; s < 8; ++s) acc[s] = bj;
#pragma unroll 8
    for (int k = 0; k < 512; ++k) {
      const float w = W2Tf[(size_t)k * 512 + t];
      const float4 h0 = hA[k][0], h1 = hA[k][1];
      acc[0] = fmaf(w, h0.x, acc[0]); acc[1] = fmaf(w, h0.y, acc[1]);
      acc[2] = fmaf(w, h0.z, acc[2]); acc[3] = fmaf(w, h0.w, acc[3]);
      acc[4] = fmaf(w, h1.x, acc[4]); acc[5] = fmaf(w, h1.y, acc[5]);
      acc[6] = fmaf(w, h1.z, acc[6]); acc[7] = fmaf(w, h1.w, acc[7]);
    }
    relu_store_mask(acc, hB, m2p + (size_t)b0 * 16, t, lane, wv);
  }
  __syncthreads();

  // ---- layer 3: K=512, hB -> hA ----
  {
    const float bj = b3[t];
#pragma unroll
    for (int s = 0; s < 8; ++s) acc[s] = bj;
#pragma unroll 8
    for (int k = 0; k < 512; ++k) {
      const float w = W3Tf[(size_t)k * 512 + t];
      const float4 h0 = hB[k][0], h1 = hB[k][1];
      acc[0] = fmaf(w, h0.x, acc[0]); acc[1] = fmaf(w, h0.y, acc[1]);
      acc[2] = fmaf(w, h0.z, acc[2]); acc[3] = fmaf(w, h0.w, acc[3]);
      acc[4] = fmaf(w, h1.x, acc[4]); acc[5] = fmaf(w, h1.y, acc[5]);
      acc[6] = fmaf(w, h1.z, acc[6]); acc[7] = fmaf(w, h1.w, acc[7]);
    }
    relu_store_mask(acc, hA, m3p + (size_t)b0 * 16, t, lane, wv);
  }
  __syncthreads();

  // ---- layer 4 (K=512, D=64) + 0.5*||s||^2 : wave wv -> sample wv ----
  {
    const int s = wv, d = lane;
    const float* hf = (const float*)&hA[0][0];  // hf[k*8 + s]
    float a4 = b4[d];
#pragma unroll 8
    for (int k = 0; k < 512; ++k)
      a4 = fmaf(W4Tf[(size_t)k * 64 + d], hf[k * 8 + s], a4);
    float sq = a4 * a4;
#pragma unroll
    for (int off = 32; off; off >>= 1) sq += __shfl_down(sq, off, 64);
    if (lane == 0) out[b0 + s] = 0.5f * sq;
  }
}

// ---------------- divergence v2: LDS-staged fragment sharing ----------------
// grid (512 sample-quads, 8 row-tiles of 64); block 256 = 4 waves.
// Wave wv -> sample g4*4+wv, rows blockIdx.y*64..+64, cols 0..64 (acc 128 AGPR).
// Per kc the block stages 16 raw fragments (slots: A2 it0-3 | A3 it0-3 |
// B1 jt0-3 | B4 jt0-3; 1KB each) into LDS buf^1 via global_load_lds (wave wv
// stages slots wv*4..wv*4+3), computes from buf, then one __syncthreads
// (drains vmcnt -> staging complete, reads done). Prefetch distance = 1 kc.
// Scalar mask words for kc+1 prefetched one iteration ahead (software pipeline)
// so their L2 latency doesn't gate the B-fragment masking.
__device__ __forceinline__ void expand_mask(uint32_t byte8, uint32_t mk[4]) {
#pragma unroll
  for (int i = 0; i < 4; ++i) {
    mk[i] = (((byte8 >> (2 * i)) & 1u) ? 0x0000FFFFu : 0u) |
            (((byte8 >> (2 * i + 1)) & 1u) ? 0xFFFF0000u : 0u);
  }
}

__global__ __launch_bounds__(256, 2) void div_kernel(
    const uint4* __restrict__ A2swz, const uint4* __restrict__ A3swz,
    const uint4* __restrict__ B1swz, const uint4* __restrict__ B4swz,
    const uint32_t* __restrict__ m1p, const uint32_t* __restrict__ m2p,
    const uint32_t* __restrict__ m3p, float* __restrict__ out) {
  __shared__ uint4 sfrag[2][16][64];  // 32KB: [buf][slot][lane]
  const int t = threadIdx.x;
  const int lane = t & 63, wv = t >> 6;
  const int l15 = lane & 15, quad = lane >> 4;
  (void)l15;
  const int g4 = blockIdx.x;
  const int rowB0 = blockIdx.y * 64;
  const int b = g4 * 4 + wv;          // this wave's sample
  const int r16b = blockIdx.y * 4;    // row-16-tile base

  // staging source base for this wave's 4 slots
  const uint4* sb = (wv == 0) ? A2swz : (wv == 1) ? A3swz : (wv == 2) ? B1swz : B4swz;

  f32x4 accC[4][4], accG[4][4];
#pragma unroll
  for (int it = 0; it < 4; ++it)
#pragma unroll
    for (int jt = 0; jt < 4; ++jt) {
      accC[it][jt] = (f32x4){0.f, 0.f, 0.f, 0.f};
      accG[it][jt] = (f32x4){0.f, 0.f, 0.f, 0.f};
    }

  const uint32_t* m1w = m1p + (size_t)b * 16;
  const uint32_t* m3w = m3p + (size_t)b * 16;

  // stage(buf, kc): wave wv stages its 4 slots
  auto stage = [&](int sbuf, int kc) {
#pragma unroll
    for (int q = 0; q < 4; ++q) {
      const size_t off = (wv < 2)
          ? ((size_t)((r16b + q) * 16 + kc) * 64 + lane)   // A2 / A3
          : ((size_t)(kc * 4 + q) * 64 + lane);            // B1 / B4
      lds_load16(sb + off, &sfrag[sbuf][wv * 4 + q][0]);
    }
  };

  stage(0, 0);
  // mask software pipeline: kc=0 words in flight during first staging drain
  uint32_t m1d_n = __builtin_amdgcn_readfirstlane(m1w[0]);
  uint32_t m3d_n = __builtin_amdgcn_readfirstlane(m3w[0]);
  __syncthreads();  // drains vmcnt(0): buf0 staged

  int buf = 0;
#pragma unroll 1
  for (int kc = 0; kc < 16; ++kc) {
    if (kc < 15) stage(buf ^ 1, kc + 1);  // prefetch next kc under compute

    const uint32_t m1d = m1d_n;
    const uint32_t m3d = m3d_n;
    if (kc < 15) {
      m1d_n = __builtin_amdgcn_readfirstlane(m1w[kc + 1]);
      m3d_n = __builtin_amdgcn_readfirstlane(m3w[kc + 1]);
    }

    uint4 a2[4], a3[4], u1[4], u4[4];
#pragma unroll
    for (int q = 0; q < 4; ++q) {
      a2[q] = sfrag[buf][q][lane];
      a3[q] = sfrag[buf][4 + q][lane];
      u1[q] = sfrag[buf][8 + q][lane];
      u4[q] = sfrag[buf][12 + q][lane];
    }

    uint32_t mk1[4], mk3[4];
    expand_mask((m1d >> (quad * 8)) & 0xFFu, mk1);
    expand_mask((m3d >> (quad * 8)) & 0xFFu, mk3);

    short8 bC[4];
#pragma unroll
    for (int jt = 0; jt < 4; ++jt) {
      U16x8 u;
      u.u = u1[jt];
      u.u.x &= mk1[0]; u.u.y &= mk1[1]; u.u.z &= mk1[2]; u.u.w &= mk1[3];
      bC[jt] = u.s;
    }
#pragma unroll
    for (int it = 0; it < 4; ++it) {
      U16x8 ua;
      ua.u = a2[it];
      const short8 af = ua.s;
#pragma unroll
      for (int jt = 0; jt < 4; ++jt)
        accC[it][jt] = __builtin_amdgcn_mfma_f32_16x16x32_bf16(af, bC[jt], accC[it][jt], 0, 0, 0);
    }
    short8 bG[4];
#pragma unroll
    for (int jt = 0; jt < 4; ++jt) {
      U16x8 u;
      u.u = u4[jt];
      u.u.x &= mk3[0]; u.u.y &= mk3[1]; u.u.z &= mk3[2]; u.u.w &= mk3[3];
      bG[jt] = u.s;
    }
#pragma unroll
    for (int it = 0; it < 4; ++it) {
      U16x8 ua;
      ua.u = a3[it];
      const short8 af = ua.s;
#pragma unroll
      for (int jt = 0; jt < 4; ++jt)
        accG[it][jt] = __builtin_amdgcn_mfma_f32_16x16x32_bf16(af, bG[jt], accG[it][jt], 0, 0, 0);
    }
    __syncthreads();  // staging of buf^1 complete + all reads of buf done
    buf ^= 1;
  }

  // epilogue: dsum = sum m2[row] * C .* G ; C/D layout: row = quad*4+reg, col = l15
  const uint32_t* m2w = m2p + (size_t)b * 16;
  float dsum = 0.f;
#pragma unroll
  for (int it = 0; it < 4; ++it) {
    const int rloc = it * 16 + quad * 4;
    const uint32_t md = m2w[(rowB0 + rloc) >> 5];
    const uint32_t bits = (md >> (rloc & 31)) & 0xFu;
    const float w0 = (bits & 1u) ? 1.f : 0.f;
    const float w1 = (bits & 2u) ? 1.f : 0.f;
    const float w2 = (bits & 4u) ? 1.f : 0.f;
    const float w3 = (bits & 8u) ? 1.f : 0.f;
#pragma unroll
    for (int jt = 0; jt < 4; ++jt) {
      dsum = fmaf(w0, accC[it][jt][0] * accG[it][jt][0], dsum);
      dsum = fmaf(w1, accC[it][jt][1] * accG[it][jt][1], dsum);
      dsum = fmaf(w2, accC[it][jt][2] * accG[it][jt][2], dsum);
      dsum = fmaf(w3, accC[it][jt][3] * accG[it][jt][3], dsum);
    }
  }
#pragma unroll
  for (int off = 32; off; off >>= 1) dsum += __shfl_down(dsum, off, 64);
  if (lane == 0) atomicAdd(out + b, dsum);
}

extern "C" void kernel_launch(void* const* d_in, const int* in_sizes, int n_in,
                              void* d_out, int out_size, void* d_ws, size_t ws_size,
                              hipStream_t stream) {
  const float* x  = (const float*)d_in[0];
  const float* W1 = (const float*)d_in[1];
  const float* b1 = (const float*)d_in[2];
  const float* W2 = (const float*)d_in[3];
  const float* b2 = (const float*)d_in[4];
  const float* W3 = (const float*)d_in[5];
  const float* b3 = (const float*)d_in[6];
  const float* W4 = (const float*)d_in[7];
  const float* b4 = (const float*)d_in[8];
  float* out = (float*)d_out;

  // workspace layout (bytes), total 3,932,160:
  char* ws = (char*)d_ws;
  uint16_t* A2swz = (uint16_t*)(ws + 0);        // 524288
  uint16_t* A3swz = (uint16_t*)(ws + 524288);   // 524288
  uint16_t* B1swz = (uint16_t*)(ws + 1048576);  // 65536
  uint16_t* B4swz = (uint16_t*)(ws + 1114112);  // 65536
  float*    W2Tf  = (float*)(ws + 1179648);     // 1048576
  float*    W3Tf  = (float*)(ws + 2228224);     // 1048576
  float*    W1Tf  = (float*)(ws + 3276800);     // 131072
  float*    W4Tf  = (float*)(ws + 3407872);     // 131072
  uint32_t* m1p   = (uint32_t*)(ws + 3538944);  // 131072 (2048 x 512 bits)
  uint32_t* m2p   = (uint32_t*)(ws + 3670016);  // 131072
  uint32_t* m3p   = (uint32_t*)(ws + 3801088);  // 131072
  if (ws_size < 3932160) return;

  convert_kernel<<<4608, 256, 0, stream>>>(W1, W2, W3, W4,
                                           A2swz, A3swz, B1swz, B4swz,
                                           W2Tf, W3Tf, W1Tf, W4Tf);
  forward_kernel<<<256, 512, 0, stream>>>(x, W1Tf, b1, W2Tf, b2, W3Tf, b3,
                                          W4Tf, b4, m1p, m2p, m3p, out);
  div_kernel<<<dim3(512, 8), 256, 0, stream>>>((const uint4*)A2swz,
                                               (const uint4*)A3swz,
                                               (const uint4*)B1swz,
                                               (const uint4*)B4swz,
                                               m1p, m2p, m3p, out);
}

// Round 4
// 281.277 us; speedup vs baseline: 1.2637x; 1.0791x over previous
//
#include <hip/hip_runtime.h>
#include <stdint.h>

// ScoreMatching: B=2048, D=64, H=512.
// out[b] = 0.5*||s_b||^2 + tr(W4 M3 W3 M2 W2 M1 W1)_b
// div_b = sum_{i,d} m2[i] * C[i,d] * G[i,d]
//   C = W2 @ (M1 .* W1)      [512 x 64]   A-frag = W2 rows,  B-frag = masked W1T rows
//   G = W3^T @ (M3 .* W4^T)  [512 x 64]   A-frag = W3T rows, B-frag = masked W4 rows
// R8 changes:
//  - div v3: R2/R3 showed nothing saturated (MFMA 35%, VALU 42%, LDS ~58%) ->
//    2-phase barrier stall (vmcnt(0) drain each kc). Now 3 LDS buffers,
//    stage kc+2 at top of kc, end-of-kc waits counted vmcnt(4) (= kc+1 done,
//    kc+2 in flight) + raw s_barrier. Masks preloaded to LDS so the loop has
//    ZERO non-staging VMEM (vmcnt arithmetic exact). MFMA math unchanged.
//  - forward v4: was ~110us at 2 waves/SIMD, 1 block/CU (3x latency stall).
//    Now 512 blocks x 512 thr, 4 samples/block -> 2 blocks/CU, 4 waves/SIMD.
//    Thread = 1 unit x 4 samples; ballot masks unchanged.

typedef __attribute__((ext_vector_type(8))) short short8;
typedef __attribute__((ext_vector_type(4))) float f32x4;

union U16x8 {
  uint4 u;
  short8 s;
};

__device__ __forceinline__ uint16_t f2bf(float f) {
  uint32_t u = __float_as_uint(f);
  uint32_t lsb = (u >> 16) & 1u;
  u += 0x7FFFu + lsb;  // round-to-nearest-even
  return (uint16_t)(u >> 16);
}

// async global->LDS, 16B per lane: lane's data lands at lds_base + lane*16.
__device__ __forceinline__ void lds_load16(const uint4* gsrc, uint4* ldst) {
  __builtin_amdgcn_global_load_lds(
      (const __attribute__((address_space(1))) void*)gsrc,
      (__attribute__((address_space(3))) void*)ldst, 16, 0, 0);
}

// ---------------- convert: build swizzled bf16 fragments + fp32 transposes ----------------
// Fragment order (16x16x32 bf16 MFMA): lane = quad*16 + l15 holds 8 contiguous
// bf16 = 16 B; A-frag element (m=l15, k=quad*8+j); B-frag (n=l15, k=quad*8+j).
// A2swz[((r16*16 + kc)*64 + lane)*8 + j] = W2 [r16*16+l15][kc*32+quad*8+j]
// A3swz[  same index                   ] = W3T[r16*16+l15][kc*32+quad*8+j]
// B1swz[((kc*4 + jt)*64 + lane)*8 + j]  = W1T[jt*16+l15 ][kc*32+quad*8+j]
// B4swz[  same index                 ]  = W4 [jt*16+l15 ][kc*32+quad*8+j]
__global__ __launch_bounds__(256) void convert_kernel(
    const float* __restrict__ W1, const float* __restrict__ W2,
    const float* __restrict__ W3, const float* __restrict__ W4,
    uint16_t* __restrict__ A2swz, uint16_t* __restrict__ A3swz,
    uint16_t* __restrict__ B1swz, uint16_t* __restrict__ B4swz,
    float* __restrict__ W2Tf, float* __restrict__ W3Tf,
    float* __restrict__ W1Tf, float* __restrict__ W4Tf) {
  const int i = blockIdx.x * 256 + threadIdx.x;
  if (i < 262144) {  // A2swz
    const int e = i;
    const int f = e >> 3, j = e & 7;
    const int lane = f & 63, fk = f >> 6;
    const int kc = fk & 15, r16 = fk >> 4;
    const int l15 = lane & 15, quad = lane >> 4;
    const int row = r16 * 16 + l15, col = kc * 32 + quad * 8 + j;
    A2swz[e] = f2bf(W2[row * 512 + col]);
  } else if (i < 524288) {  // A3swz (= W3 transposed)
    const int e = i - 262144;
    const int f = e >> 3, j = e & 7;
    const int lane = f & 63, fk = f >> 6;
    const int kc = fk & 15, r16 = fk >> 4;
    const int l15 = lane & 15, quad = lane >> 4;
    const int row = r16 * 16 + l15, col = kc * 32 + quad * 8 + j;
    A3swz[e] = f2bf(W3[col * 512 + row]);
  } else if (i < 557056) {  // B1swz (= W1 transposed)
    const int e = i - 524288;
    const int f = e >> 3, j = e & 7;
    const int lane = f & 63, fk = f >> 6;
    const int kc = fk >> 2, jt = fk & 3;
    const int l15 = lane & 15, quad = lane >> 4;
    const int d = jt * 16 + l15, col = kc * 32 + quad * 8 + j;
    B1swz[e] = f2bf(W1[col * 64 + d]);
  } else if (i < 589824) {  // B4swz (= W4 row-major)
    const int e = i - 557056;
    const int f = e >> 3, j = e & 7;
    const int lane = f & 63, fk = f >> 6;
    const int kc = fk >> 2, jt = fk & 3;
    const int l15 = lane & 15, quad = lane >> 4;
    const int d = jt * 16 + l15, col = kc * 32 + quad * 8 + j;
    B4swz[e] = f2bf(W4[d * 512 + col]);
  } else if (i < 851968) {  // W2Tf [k][j]
    const int e = i - 589824;
    const int k = e >> 9, jj = e & 511;
    W2Tf[e] = W2[jj * 512 + k];
  } else if (i < 1114112) {  // W3Tf [k][j]
    const int e = i - 851968;
    const int k = e >> 9, jj = e & 511;
    W3Tf[e] = W3[jj * 512 + k];
  } else if (i < 1146880) {  // W1Tf [k][j], k<64
    const int e = i - 1114112;
    const int k = e >> 9, jj = e & 511;
    W1Tf[e] = W1[jj * 64 + k];
  } else if (i < 1179648) {  // W4Tf [k][d]
    const int e = i - 1146880;
    const int k = e >> 6, d = e & 63;
    W4Tf[e] = W4[d * 512 + k];
  }
}

// ---------------- forward v4 (fp32): ballot masks, unit-per-thread ----------------
// 512 blocks x 512 threads (8 waves); 4 samples/block -> 2 blocks/CU,
// 4 waves/SIMD. Thread t owns unit j=t for 4 samples. Per k: one coalesced
// 4B W-load + one broadcast float4 LDS read + 4 FMA.
// Mask: wave w covers units w*64..w*64+63 -> __ballot(a>0) = words 2w, 2w+1 of
// the packed mask (bit u of word W = unit W*32+u), stored by lane 0. No atomics.
__device__ __forceinline__ void relu_store_mask4(
    float acc[4], float (*hdst)[4], uint32_t* __restrict__ mbase,
    int t, int lane, int wv) {
#pragma unroll
  for (int s = 0; s < 4; ++s) {
    const unsigned long long bal = __ballot(acc[s] > 0.f);
    if (lane == 0) {
      uint2 w2;
      w2.x = (uint32_t)bal;
      w2.y = (uint32_t)(bal >> 32);
      *(uint2*)(mbase + (size_t)s * 16 + 2 * wv) = w2;
    }
  }
  float4 r;
  r.x = acc[0] > 0.f ? acc[0] : 0.f;
  r.y = acc[1] > 0.f ? acc[1] : 0.f;
  r.z = acc[2] > 0.f ? acc[2] : 0.f;
  r.w = acc[3] > 0.f ? acc[3] : 0.f;
  *(float4*)&hdst[t][0] = r;
}

__global__ __launch_bounds__(512) void forward_kernel(
    const float* __restrict__ x,
    const float* __restrict__ W1Tf, const float* __restrict__ b1,
    const float* __restrict__ W2Tf, const float* __restrict__ b2,
    const float* __restrict__ W3Tf, const float* __restrict__ b3,
    const float* __restrict__ W4Tf, const float* __restrict__ b4,
    uint32_t* __restrict__ m1p, uint32_t* __restrict__ m2p,
    uint32_t* __restrict__ m3p, float* __restrict__ out) {
  __shared__ float xs[64][4];   // [k][sample]
  __shared__ float hA[512][4];  // [unit][sample]
  __shared__ float hB[512][4];
  const int t = threadIdx.x;
  const int lane = t & 63, wv = t >> 6;
  const int b0 = blockIdx.x * 4;

  if (t < 256) {
    const int k = t >> 2, s = t & 3;  // 256 threads cover 4 samples x 64 k
    xs[k][s] = x[(size_t)(b0 + s) * 64 + k];
  }
  __syncthreads();

  float acc[4];

  // ---- layer 1: K=64 ----
  {
    const float bj = b1[t];
#pragma unroll
    for (int s = 0; s < 4; ++s) acc[s] = bj;
#pragma unroll 8
    for (int k = 0; k < 64; ++k) {
      const float w = W1Tf[(size_t)k * 512 + t];
      const float4 h = *(const float4*)&xs[k][0];
      acc[0] = fmaf(w, h.x, acc[0]); acc[1] = fmaf(w, h.y, acc[1]);
      acc[2] = fmaf(w, h.z, acc[2]); acc[3] = fmaf(w, h.w, acc[3]);
    }
    relu_store_mask4(acc, hA, m1p + (size_t)b0 * 16, t, lane, wv);
  }
  __syncthreads();

  // ---- layer 2: K=512, hA -> hB ----
  {
    const float bj = b2[t];
#pragma unroll
    for (int s = 0; s < 4; ++s) acc[s] = bj;
#pragma unroll 8
    for (int k = 0; k < 512; ++k) {
      const float w = W2Tf[(size_t)k * 512 + t];
      const float4 h = *(const float4*)&hA[k][0];
      acc[0] = fmaf(w, h.x, acc[0]); acc[1] = fmaf(w, h.y, acc[1]);
      acc[2] = fmaf(w, h.z, acc[2]); acc[3] = fmaf(w, h.w, acc[3]);
    }
    relu_store_mask4(acc, hB, m2p + (size_t)b0 * 16, t, lane, wv);
  }
  __syncthreads();

  // ---- layer 3: K=512, hB -> hA ----
  {
    const float bj = b3[t];
#pragma unroll
    for (int s = 0; s < 4; ++s) acc[s] = bj;
#pragma unroll 8
    for (int k = 0; k < 512; ++k) {
      const float w = W3Tf[(size_t)k * 512 + t];
      const float4 h = *(const float4*)&hB[k][0];
      acc[0] = fmaf(w, h.x, acc[0]); acc[1] = fmaf(w, h.y, acc[1]);
      acc[2] = fmaf(w, h.z, acc[2]); acc[3] = fmaf(w, h.w, acc[3]);
    }
    relu_store_mask4(acc, hA, m3p + (size_t)b0 * 16, t, lane, wv);
  }
  __syncthreads();

  // ---- layer 4 (K=512, D=64) + 0.5*||s||^2 : wave wv (<4) -> sample wv ----
  if (wv < 4) {
    const int s = wv, d = lane;
    float a4 = b4[d];
#pragma unroll 8
    for (int k = 0; k < 512; ++k)
      a4 = fmaf(W4Tf[(size_t)k * 64 + d], hA[k][s], a4);
    float sq = a4 * a4;
#pragma unroll
    for (int off = 32; off; off >>= 1) sq += __shfl_down(sq, off, 64);
    if (lane == 0) out[b0 + s] = 0.5f * sq;
  }
}

// ---------------- divergence v3: 3-buf staging, counted vmcnt, raw barriers ----------------
// grid (512 sample-quads, 8 row-tiles of 64); block 256 = 4 waves.
// Wave wv -> sample g4*4+wv, rows blockIdx.y*64..+64, cols 0..64 (acc 128 AGPR).
// Per kc: stage kc+2 into buf[(kc+2)%3] (wave wv stages slots wv*4..wv*4+3),
// compute from buf[kc%3], then s_waitcnt vmcnt(4) (kc+1 staged, kc+2 still in
// flight -- NEVER drain to 0 in steady state) + raw s_barrier. Masks preloaded
// to LDS so the loop body has zero non-staging VMEM (vmcnt count is exact).
__device__ __forceinline__ void expand_mask(uint32_t byte8, uint32_t mk[4]) {
#pragma unroll
  for (int i = 0; i < 4; ++i) {
    mk[i] = (((byte8 >> (2 * i)) & 1u) ? 0x0000FFFFu : 0u) |
            (((byte8 >> (2 * i + 1)) & 1u) ? 0xFFFF0000u : 0u);
  }
}

__global__ __launch_bounds__(256, 2) void div_kernel(
    const uint4* __restrict__ A2swz, const uint4* __restrict__ A3swz,
    const uint4* __restrict__ B1swz, const uint4* __restrict__ B4swz,
    const uint32_t* __restrict__ m1p, const uint32_t* __restrict__ m2p,
    const uint32_t* __restrict__ m3p, float* __restrict__ out) {
  __shared__ uint4 sfrag[3][16][64];    // 48KB: [buf][slot][lane]
  __shared__ uint32_t smask[4][2][16];  // [wave][m1|m3][kc] (wave-private)
  const int t = threadIdx.x;
  const int lane = t & 63, wv = t >> 6;
  const int quad = lane >> 4;
  const int g4 = blockIdx.x;
  const int rowB0 = blockIdx.y * 64;
  const int b = g4 * 4 + wv;          // this wave's sample
  const int r16b = blockIdx.y * 4;    // row-16-tile base

  // staging source base for this wave's 4 slots
  const uint4* sb = (wv == 0) ? A2swz : (wv == 1) ? A3swz : (wv == 2) ? B1swz : B4swz;

  f32x4 accC[4][4], accG[4][4];
#pragma unroll
  for (int it = 0; it < 4; ++it)
#pragma unroll
    for (int jt = 0; jt < 4; ++jt) {
      accC[it][jt] = (f32x4){0.f, 0.f, 0.f, 0.f};
      accG[it][jt] = (f32x4){0.f, 0.f, 0.f, 0.f};
    }

  // per-wave mask preload into LDS (wave reads only its own rows -> no barrier
  // needed for these; in-wave ds ordering is by lgkmcnt).
  {
    const uint32_t* m1w = m1p + (size_t)b * 16;
    const uint32_t* m3w = m3p + (size_t)b * 16;
    if (lane < 16) smask[wv][0][lane] = m1w[lane];
    else if (lane < 32) smask[wv][1][lane & 15] = m3w[lane & 15];
  }

  // stage(buf, kc): wave wv stages its 4 slots
  auto stage = [&](int sbuf, int kc) {
#pragma unroll
    for (int q = 0; q < 4; ++q) {
      const size_t off = (wv < 2)
          ? ((size_t)((r16b + q) * 16 + kc) * 64 + lane)   // A2 / A3
          : ((size_t)(kc * 4 + q) * 64 + lane);            // B1 / B4
      lds_load16(sb + off, &sfrag[sbuf][wv * 4 + q][0]);
    }
  };

  stage(0, 0);
  stage(1, 1);
  __builtin_amdgcn_sched_barrier(0);
  asm volatile("s_waitcnt vmcnt(4)" ::: "memory");  // kc=0 staging complete
  __builtin_amdgcn_s_barrier();
  __builtin_amdgcn_sched_barrier(0);

#pragma unroll 1
  for (int kc = 0; kc < 16; ++kc) {
    const int rb = kc % 3;
    if (kc < 14) stage((kc + 2) % 3, kc + 2);  // keep 2 kc in flight

    const uint32_t m1d = __builtin_amdgcn_readfirstlane(smask[wv][0][kc]);
    const uint32_t m3d = __builtin_amdgcn_readfirstlane(smask[wv][1][kc]);

    uint4 a2[4], a3[4], u1[4], u4[4];
#pragma unroll
    for (int q = 0; q < 4; ++q) {
      a2[q] = sfrag[rb][q][lane];
      a3[q] = sfrag[rb][4 + q][lane];
      u1[q] = sfrag[rb][8 + q][lane];
      u4[q] = sfrag[rb][12 + q][lane];
    }

    uint32_t mk1[4], mk3[4];
    expand_mask((m1d >> (quad * 8)) & 0xFFu, mk1);
    expand_mask((m3d >> (quad * 8)) & 0xFFu, mk3);

    short8 bC[4];
#pragma unroll
    for (int jt = 0; jt < 4; ++jt) {
      U16x8 u;
      u.u = u1[jt];
      u.u.x &= mk1[0]; u.u.y &= mk1[1]; u.u.z &= mk1[2]; u.u.w &= mk1[3];
      bC[jt] = u.s;
    }
#pragma unroll
    for (int it = 0; it < 4; ++it) {
      U16x8 ua;
      ua.u = a2[it];
      const short8 af = ua.s;
#pragma unroll
      for (int jt = 0; jt < 4; ++jt)
        accC[it][jt] = __builtin_amdgcn_mfma_f32_16x16x32_bf16(af, bC[jt], accC[it][jt], 0, 0, 0);
    }
    short8 bG[4];
#pragma unroll
    for (int jt = 0; jt < 4; ++jt) {
      U16x8 u;
      u.u = u4[jt];
      u.u.x &= mk3[0]; u.u.y &= mk3[1]; u.u.z &= mk3[2]; u.u.w &= mk3[3];
      bG[jt] = u.s;
    }
#pragma unroll
    for (int it = 0; it < 4; ++it) {
      U16x8 ua;
      ua.u = a3[it];
      const short8 af = ua.s;
#pragma unroll
      for (int jt = 0; jt < 4; ++jt)
        accG[it][jt] = __builtin_amdgcn_mfma_f32_16x16x32_bf16(af, bG[jt], accG[it][jt], 0, 0, 0);
    }

    // counted wait: kc+1's staging (oldest 4) done; kc+2's 4 stay in flight.
    if (kc < 14) {
      asm volatile("s_waitcnt vmcnt(4)" ::: "memory");
    } else if (kc == 14) {
      asm volatile("s_waitcnt vmcnt(0)" ::: "memory");  // drain last stage
    }
    if (kc < 15) {
      __builtin_amdgcn_s_barrier();
      __builtin_amdgcn_sched_barrier(0);  // no ds_read hoisting above barrier
    }
  }

  // epilogue: dsum = sum m2[row] * C .* G ; C/D layout: row = quad*4+reg, col = l15
  const uint32_t* m2w = m2p + (size_t)b * 16;
  float dsum = 0.f;
#pragma unroll
  for (int it = 0; it < 4; ++it) {
    const int rloc = it * 16 + quad * 4;
    const uint32_t md = m2w[(rowB0 + rloc) >> 5];
    const uint32_t bits = (md >> (rloc & 31)) & 0xFu;
    const float w0 = (bits & 1u) ? 1.f : 0.f;
    const float w1 = (bits & 2u) ? 1.f : 0.f;
    const float w2 = (bits & 4u) ? 1.f : 0.f;
    const float w3 = (bits & 8u) ? 1.f : 0.f;
#pragma unroll
    for (int jt = 0; jt < 4; ++jt) {
      dsum = fmaf(w0, accC[it][jt][0] * accG[it][jt][0], dsum);
      dsum = fmaf(w1, accC[it][jt][1] * accG[it][jt][1], dsum);
      dsum = fmaf(w2, accC[it][jt][2] * accG[it][jt][2], dsum);
      dsum = fmaf(w3, accC[it][jt][3] * accG[it][jt][3], dsum);
    }
  }
#pragma unroll
  for (int off = 32; off; off >>= 1) dsum += __shfl_down(dsum, off, 64);
  if (lane == 0) atomicAdd(out + b, dsum);
}

extern "C" void kernel_launch(void* const* d_in, const int* in_sizes, int n_in,
                              void* d_out, int out_size, void* d_ws, size_t ws_size,
                              hipStream_t stream) {
  const float* x  = (const float*)d_in[0];
  const float* W1 = (const float*)d_in[1];
  const float* b1 = (const float*)d_in[2];
  const float* W2 = (const float*)d_in[3];
  const float* b2 = (const float*)d_in[4];
  const float* W3 = (const float*)d_in[5];
  const float* b3 = (const float*)d_in[6];
  const float* W4 = (const float*)d_in[7];
  const float* b4 = (const float*)d_in[8];
  float* out = (float*)d_out;

  // workspace layout (bytes), total 3,932,160:
  char* ws = (char*)d_ws;
  uint16_t* A2swz = (uint16_t*)(ws + 0);        // 524288
  uint16_t* A3swz = (uint16_t*)(ws + 524288);   // 524288
  uint16_t* B1swz = (uint16_t*)(ws + 1048576);  // 65536
  uint16_t* B4swz = (uint16_t*)(ws + 1114112);  // 65536
  float*    W2Tf  = (float*)(ws + 1179648);     // 1048576
  float*    W3Tf  = (float*)(ws + 2228224);     // 1048576
  float*    W1Tf  = (float*)(ws + 3276800);     // 131072
  float*    W4Tf  = (float*)(ws + 3407872);     // 131072
  uint32_t* m1p   = (uint32_t*)(ws + 3538944);  // 131072 (2048 x 512 bits)
  uint32_t* m2p   = (uint32_t*)(ws + 3670016);  // 131072
  uint32_t* m3p   = (uint32_t*)(ws + 3801088);  // 131072
  if (ws_size < 3932160) return;

  convert_kernel<<<4608, 256, 0, stream>>>(W1, W2, W3, W4,
                                           A2swz, A3swz, B1swz, B4swz,
                                           W2Tf, W3Tf, W1Tf, W4Tf);
  forward_kernel<<<512, 512, 0, stream>>>(x, W1Tf, b1, W2Tf, b2, W3Tf, b3,
                                          W4Tf, b4, m1p, m2p, m3p, out);
  div_kernel<<<dim3(512, 8), 256, 0, stream>>>((const uint4*)A2swz,
                                               (const uint4*)A3swz,
                                               (const uint4*)B1swz,
                                               (const uint4*)B4swz,
                                               m1p, m2p, m3p, out);
}

// Round 5
// 280.040 us; speedup vs baseline: 1.2693x; 1.0044x over previous
//
#include <hip/hip_runtime.h>
#include <stdint.h>

// ScoreMatching: B=2048, D=64, H=512.
// out[b] = 0.5*||s_b||^2 + tr(W4 M3 W3 M2 W2 M1 W1)_b
// div_b = sum_{i,d} m2[i] * C[i,d] * G[i,d]
//   C = W2 @ (M1 .* W1)      [512 x 64]   A-frag = W2 rows,  B-frag = masked W1T rows
//   G = W3^T @ (M3 .* W4^T)  [512 x 64]   A-frag = W3T rows, B-frag = masked W4 rows
// R9 changes:
//  - forward v5: R4 showed occupancy alone didn't fix forward (~110us vs ~30us
//    floor). Root cause: per-k W-load->FMA dep with only unroll-8 lookahead.
//    Now explicit 2x8 register double-buffer (named wA/wB, static indexing):
//    loads lead use by a full 8-k half-step for the whole K loop. Layer 4 split
//    across all 8 waves (k-halves + LDS combine; 4-way partial accs to break
//    the serial FMA chain).
//  - div v4: per-kc split into C-phase / G-phase (8 ds_reads + mask + 16 MFMA
//    each), MFMA clusters wrapped in s_setprio(1/0) (T5; cross-block wave
//    diversity exists at 2 blocks/CU). Staging/vmcnt/epilogue unchanged.

typedef __attribute__((ext_vector_type(8))) short short8;
typedef __attribute__((ext_vector_type(4))) float f32x4;

union U16x8 {
  uint4 u;
  short8 s;
};

__device__ __forceinline__ uint16_t f2bf(float f) {
  uint32_t u = __float_as_uint(f);
  uint32_t lsb = (u >> 16) & 1u;
  u += 0x7FFFu + lsb;  // round-to-nearest-even
  return (uint16_t)(u >> 16);
}

// async global->LDS, 16B per lane: lane's data lands at lds_base + lane*16.
__device__ __forceinline__ void lds_load16(const uint4* gsrc, uint4* ldst) {
  __builtin_amdgcn_global_load_lds(
      (const __attribute__((address_space(1))) void*)gsrc,
      (__attribute__((address_space(3))) void*)ldst, 16, 0, 0);
}

// ---------------- convert: build swizzled bf16 fragments + fp32 transposes ----------------
// Fragment order (16x16x32 bf16 MFMA): lane = quad*16 + l15 holds 8 contiguous
// bf16 = 16 B; A-frag element (m=l15, k=quad*8+j); B-frag (n=l15, k=quad*8+j).
// A2swz[((r16*16 + kc)*64 + lane)*8 + j] = W2 [r16*16+l15][kc*32+quad*8+j]
// A3swz[  same index                   ] = W3T[r16*16+l15][kc*32+quad*8+j]
// B1swz[((kc*4 + jt)*64 + lane)*8 + j]  = W1T[jt*16+l15 ][kc*32+quad*8+j]
// B4swz[  same index                 ]  = W4 [jt*16+l15 ][kc*32+quad*8+j]
__global__ __launch_bounds__(256) void convert_kernel(
    const float* __restrict__ W1, const float* __restrict__ W2,
    const float* __restrict__ W3, const float* __restrict__ W4,
    uint16_t* __restrict__ A2swz, uint16_t* __restrict__ A3swz,
    uint16_t* __restrict__ B1swz, uint16_t* __restrict__ B4swz,
    float* __restrict__ W2Tf, float* __restrict__ W3Tf,
    float* __restrict__ W1Tf, float* __restrict__ W4Tf) {
  const int i = blockIdx.x * 256 + threadIdx.x;
  if (i < 262144) {  // A2swz
    const int e = i;
    const int f = e >> 3, j = e & 7;
    const int lane = f & 63, fk = f >> 6;
    const int kc = fk & 15, r16 = fk >> 4;
    const int l15 = lane & 15, quad = lane >> 4;
    const int row = r16 * 16 + l15, col = kc * 32 + quad * 8 + j;
    A2swz[e] = f2bf(W2[row * 512 + col]);
  } else if (i < 524288) {  // A3swz (= W3 transposed)
    const int e = i - 262144;
    const int f = e >> 3, j = e & 7;
    const int lane = f & 63, fk = f >> 6;
    const int kc = fk & 15, r16 = fk >> 4;
    const int l15 = lane & 15, quad = lane >> 4;
    const int row = r16 * 16 + l15, col = kc * 32 + quad * 8 + j;
    A3swz[e] = f2bf(W3[col * 512 + row]);
  } else if (i < 557056) {  // B1swz (= W1 transposed)
    const int e = i - 524288;
    const int f = e >> 3, j = e & 7;
    const int lane = f & 63, fk = f >> 6;
    const int kc = fk >> 2, jt = fk & 3;
    const int l15 = lane & 15, quad = lane >> 4;
    const int d = jt * 16 + l15, col = kc * 32 + quad * 8 + j;
    B1swz[e] = f2bf(W1[col * 64 + d]);
  } else if (i < 589824) {  // B4swz (= W4 row-major)
    const int e = i - 557056;
    const int f = e >> 3, j = e & 7;
    const int lane = f & 63, fk = f >> 6;
    const int kc = fk >> 2, jt = fk & 3;
    const int l15 = lane & 15, quad = lane >> 4;
    const int d = jt * 16 + l15, col = kc * 32 + quad * 8 + j;
    B4swz[e] = f2bf(W4[d * 512 + col]);
  } else if (i < 851968) {  // W2Tf [k][j]
    const int e = i - 589824;
    const int k = e >> 9, jj = e & 511;
    W2Tf[e] = W2[jj * 512 + k];
  } else if (i < 1114112) {  // W3Tf [k][j]
    const int e = i - 851968;
    const int k = e >> 9, jj = e & 511;
    W3Tf[e] = W3[jj * 512 + k];
  } else if (i < 1146880) {  // W1Tf [k][j], k<64
    const int e = i - 1114112;
    const int k = e >> 9, jj = e & 511;
    W1Tf[e] = W1[jj * 64 + k];
  } else if (i < 1179648) {  // W4Tf [k][d]
    const int e = i - 1146880;
    const int k = e >> 6, d = e & 63;
    W4Tf[e] = W4[d * 512 + k];
  }
}

// ---------------- forward v5 (fp32): W register double-buffer ----------------
// 512 blocks x 512 threads (8 waves); 4 samples/block -> 2 blocks/CU,
// 4 waves/SIMD. Thread t owns unit j=t for 4 samples.
// Hidden-layer inner loop: named wA[8]/wB[8] register double buffer; the 8
// loads for the NEXT half-step are issued before computing the current one,
// so global latency is covered by ~100cyc of FMA x 4 waves/SIMD.
// Mask: wave w covers units w*64..w*64+63 -> __ballot(a>0) = words 2w, 2w+1.
__device__ __forceinline__ void relu_store_mask4(
    float acc[4], float (*hdst)[4], uint32_t* __restrict__ mbase,
    int t, int lane, int wv) {
#pragma unroll
  for (int s = 0; s < 4; ++s) {
    const unsigned long long bal = __ballot(acc[s] > 0.f);
    if (lane == 0) {
      uint2 w2;
      w2.x = (uint32_t)bal;
      w2.y = (uint32_t)(bal >> 32);
      *(uint2*)(mbase + (size_t)s * 16 + 2 * wv) = w2;
    }
  }
  float4 r;
  r.x = acc[0] > 0.f ? acc[0] : 0.f;
  r.y = acc[1] > 0.f ? acc[1] : 0.f;
  r.z = acc[2] > 0.f ? acc[2] : 0.f;
  r.w = acc[3] > 0.f ? acc[3] : 0.f;
  *(float4*)&hdst[t][0] = r;
}

__device__ __forceinline__ void fwd_layer(
    const float* __restrict__ WT, const float* __restrict__ bias,
    const float (* __restrict__ src)[4], float (* __restrict__ dst)[4],
    uint32_t* __restrict__ mbase, int t, int lane, int wv, int K) {
  float acc[4];
  {
    const float bj = bias[t];
    acc[0] = bj; acc[1] = bj; acc[2] = bj; acc[3] = bj;
  }
  const float* Wp = WT + t;
  float wA[8], wB[8];
#pragma unroll
  for (int j = 0; j < 8; ++j) wA[j] = Wp[(size_t)j * 512];
#pragma unroll 1
  for (int kb = 0; kb < K; kb += 16) {
#pragma unroll
    for (int j = 0; j < 8; ++j) wB[j] = Wp[(size_t)(kb + 8 + j) * 512];
#pragma unroll
    for (int j = 0; j < 8; ++j) {
      const float4 h = *(const float4*)&src[kb + j][0];
      const float w = wA[j];
      acc[0] = fmaf(w, h.x, acc[0]); acc[1] = fmaf(w, h.y, acc[1]);
      acc[2] = fmaf(w, h.z, acc[2]); acc[3] = fmaf(w, h.w, acc[3]);
    }
    if (kb + 16 < K) {
#pragma unroll
      for (int j = 0; j < 8; ++j) wA[j] = Wp[(size_t)(kb + 16 + j) * 512];
    }
#pragma unroll
    for (int j = 0; j < 8; ++j) {
      const float4 h = *(const float4*)&src[kb + 8 + j][0];
      const float w = wB[j];
      acc[0] = fmaf(w, h.x, acc[0]); acc[1] = fmaf(w, h.y, acc[1]);
      acc[2] = fmaf(w, h.z, acc[2]); acc[3] = fmaf(w, h.w, acc[3]);
    }
  }
  relu_store_mask4(acc, dst, mbase, t, lane, wv);
}

__global__ __launch_bounds__(512) void forward_kernel(
    const float* __restrict__ x,
    const float* __restrict__ W1Tf, const float* __restrict__ b1,
    const float* __restrict__ W2Tf, const float* __restrict__ b2,
    const float* __restrict__ W3Tf, const float* __restrict__ b3,
    const float* __restrict__ W4Tf, const float* __restrict__ b4,
    uint32_t* __restrict__ m1p, uint32_t* __restrict__ m2p,
    uint32_t* __restrict__ m3p, float* __restrict__ out) {
  __shared__ float xs[64][4];   // [k][sample]
  __shared__ float hA[512][4];  // [unit][sample]
  __shared__ float hB[512][4];
  __shared__ float p4[4][2][64];  // layer-4 partials [sample][k-half][d]
  const int t = threadIdx.x;
  const int lane = t & 63, wv = t >> 6;
  const int b0 = blockIdx.x * 4;

  if (t < 256) {
    const int k = t >> 2, s = t & 3;  // 256 threads cover 4 samples x 64 k
    xs[k][s] = x[(size_t)(b0 + s) * 64 + k];
  }
  __syncthreads();

  fwd_layer(W1Tf, b1, xs, hA, m1p + (size_t)b0 * 16, t, lane, wv, 64);
  __syncthreads();
  fwd_layer(W2Tf, b2, hA, hB, m2p + (size_t)b0 * 16, t, lane, wv, 512);
  __syncthreads();
  fwd_layer(W3Tf, b3, hB, hA, m3p + (size_t)b0 * 16, t, lane, wv, 512);
  __syncthreads();

  // ---- layer 4 (K=512, D=64) + 0.5*||s||^2 : 8 waves, k-halves ----
  {
    const int s = wv & 3, hh = wv >> 2, d = lane;
    const int k0 = hh * 256;
    const float* Wp = W4Tf + (size_t)k0 * 64 + d;
    float ap[4] = {0.f, 0.f, 0.f, 0.f};
    float wA[8], wB[8];
#pragma unroll
    for (int j = 0; j < 8; ++j) wA[j] = Wp[(size_t)j * 64];
#pragma unroll 1
    for (int kb = 0; kb < 256; kb += 16) {
#pragma unroll
      for (int j = 0; j < 8; ++j) wB[j] = Wp[(size_t)(kb + 8 + j) * 64];
#pragma unroll
      for (int j = 0; j < 8; ++j)
        ap[j & 3] = fmaf(wA[j], hA[k0 + kb + j][s], ap[j & 3]);
      if (kb + 16 < 256) {
#pragma unroll
        for (int j = 0; j < 8; ++j) wA[j] = Wp[(size_t)(kb + 16 + j) * 64];
      }
#pragma unroll
      for (int j = 0; j < 8; ++j)
        ap[j & 3] = fmaf(wB[j], hA[k0 + kb + 8 + j][s], ap[j & 3]);
    }
    p4[s][hh][d] = (ap[0] + ap[1]) + (ap[2] + ap[3]);
  }
  __syncthreads();
  if (wv < 4) {
    const int s = wv, d = lane;
    const float a4 = p4[s][0][d] + p4[s][1][d] + b4[d];
    float sq = a4 * a4;
#pragma unroll
    for (int off = 32; off; off >>= 1) sq += __shfl_down(sq, off, 64);
    if (lane == 0) out[b0 + s] = 0.5f * sq;
  }
}

// ---------------- divergence v4: 3-buf staging, counted vmcnt, C/G phases ----------------
// grid (512 sample-quads, 8 row-tiles of 64); block 256 = 4 waves.
// Wave wv -> sample g4*4+wv, rows blockIdx.y*64..+64, cols 0..64 (acc 128 AGPR).
// Per kc: stage kc+2 into buf[(kc+2)%3] (wave wv stages slots wv*4..wv*4+3),
// then C-phase {8 ds_reads, mask, 16 MFMA in setprio(1)} then G-phase (same),
// then s_waitcnt vmcnt(4) (kc+1 staged, kc+2 in flight -- NEVER 0 in steady
// state) + raw s_barrier. Masks preloaded to LDS: loop has zero non-staging
// VMEM so the vmcnt count is exact.
__device__ __forceinline__ void expand_mask(uint32_t byte8, uint32_t mk[4]) {
#pragma unroll
  for (int i = 0; i < 4; ++i) {
    mk[i] = (((byte8 >> (2 * i)) & 1u) ? 0x0000FFFFu : 0u) |
            (((byte8 >> (2 * i + 1)) & 1u) ? 0xFFFF0000u : 0u);
  }
}

__global__ __launch_bounds__(256, 2) void div_kernel(
    const uint4* __restrict__ A2swz, const uint4* __restrict__ A3swz,
    const uint4* __restrict__ B1swz, const uint4* __restrict__ B4swz,
    const uint32_t* __restrict__ m1p, const uint32_t* __restrict__ m2p,
    const uint32_t* __restrict__ m3p, float* __restrict__ out) {
  __shared__ uint4 sfrag[3][16][64];    // 48KB: [buf][slot][lane]
  __shared__ uint32_t smask[4][2][16];  // [wave][m1|m3][kc] (wave-private)
  const int t = threadIdx.x;
  const int lane = t & 63, wv = t >> 6;
  const int quad = lane >> 4;
  const int g4 = blockIdx.x;
  const int rowB0 = blockIdx.y * 64;
  const int b = g4 * 4 + wv;          // this wave's sample
  const int r16b = blockIdx.y * 4;    // row-16-tile base

  // staging source base for this wave's 4 slots
  const uint4* sb = (wv == 0) ? A2swz : (wv == 1) ? A3swz : (wv == 2) ? B1swz : B4swz;

  f32x4 accC[4][4], accG[4][4];
#pragma unroll
  for (int it = 0; it < 4; ++it)
#pragma unroll
    for (int jt = 0; jt < 4; ++jt) {
      accC[it][jt] = (f32x4){0.f, 0.f, 0.f, 0.f};
      accG[it][jt] = (f32x4){0.f, 0.f, 0.f, 0.f};
    }

  // per-wave mask preload into LDS (wave reads only its own rows -> no barrier
  // needed for these; in-wave ds ordering is by lgkmcnt).
  {
    const uint32_t* m1w = m1p + (size_t)b * 16;
    const uint32_t* m3w = m3p + (size_t)b * 16;
    if (lane < 16) smask[wv][0][lane] = m1w[lane];
    else if (lane < 32) smask[wv][1][lane & 15] = m3w[lane & 15];
  }

  // stage(buf, kc): wave wv stages its 4 slots
  auto stage = [&](int sbuf, int kc) {
#pragma unroll
    for (int q = 0; q < 4; ++q) {
      const size_t off = (wv < 2)
          ? ((size_t)((r16b + q) * 16 + kc) * 64 + lane)   // A2 / A3
          : ((size_t)(kc * 4 + q) * 64 + lane);            // B1 / B4
      lds_load16(sb + off, &sfrag[sbuf][wv * 4 + q][0]);
    }
  };

  stage(0, 0);
  stage(1, 1);
  __builtin_amdgcn_sched_barrier(0);
  asm volatile("s_waitcnt vmcnt(4)" ::: "memory");  // kc=0 staging complete
  __builtin_amdgcn_s_barrier();
  __builtin_amdgcn_sched_barrier(0);

#pragma unroll 1
  for (int kc = 0; kc < 16; ++kc) {
    const int rb = kc % 3;
    if (kc < 14) stage((kc + 2) % 3, kc + 2);  // keep 2 kc in flight

    // ---- C phase ----
    {
      const uint32_t m1d = __builtin_amdgcn_readfirstlane(smask[wv][0][kc]);
      uint32_t mk1[4];
      expand_mask((m1d >> (quad * 8)) & 0xFFu, mk1);

      uint4 a2[4], u1[4];
#pragma unroll
      for (int q = 0; q < 4; ++q) {
        a2[q] = sfrag[rb][q][lane];
        u1[q] = sfrag[rb][8 + q][lane];
      }
      short8 bC[4];
#pragma unroll
      for (int jt = 0; jt < 4; ++jt) {
        U16x8 u;
        u.u = u1[jt];
        u.u.x &= mk1[0]; u.u.y &= mk1[1]; u.u.z &= mk1[2]; u.u.w &= mk1[3];
        bC[jt] = u.s;
      }
      __builtin_amdgcn_s_setprio(1);
#pragma unroll
      for (int it = 0; it < 4; ++it) {
        U16x8 ua;
        ua.u = a2[it];
        const short8 af = ua.s;
#pragma unroll
        for (int jt = 0; jt < 4; ++jt)
          accC[it][jt] = __builtin_amdgcn_mfma_f32_16x16x32_bf16(af, bC[jt], accC[it][jt], 0, 0, 0);
      }
      __builtin_amdgcn_s_setprio(0);
    }

    // ---- G phase ----
    {
      const uint32_t m3d = __builtin_amdgcn_readfirstlane(smask[wv][1][kc]);
      uint32_t mk3[4];
      expand_mask((m3d >> (quad * 8)) & 0xFFu, mk3);

      uint4 a3[4], u4[4];
#pragma unroll
      for (int q = 0; q < 4; ++q) {
        a3[q] = sfrag[rb][4 + q][lane];
        u4[q] = sfrag[rb][12 + q][lane];
      }
      short8 bG[4];
#pragma unroll
      for (int jt = 0; jt < 4; ++jt) {
        U16x8 u;
        u.u = u4[jt];
        u.u.x &= mk3[0]; u.u.y &= mk3[1]; u.u.z &= mk3[2]; u.u.w &= mk3[3];
        bG[jt] = u.s;
      }
      __builtin_amdgcn_s_setprio(1);
#pragma unroll
      for (int it = 0; it < 4; ++it) {
        U16x8 ua;
        ua.u = a3[it];
        const short8 af = ua.s;
#pragma unroll
        for (int jt = 0; jt < 4; ++jt)
          accG[it][jt] = __builtin_amdgcn_mfma_f32_16x16x32_bf16(af, bG[jt], accG[it][jt], 0, 0, 0);
      }
      __builtin_amdgcn_s_setprio(0);
    }

    // counted wait: kc+1's staging (oldest 4) done; kc+2's 4 stay in flight.
    if (kc < 14) {
      asm volatile("s_waitcnt vmcnt(4)" ::: "memory");
    } else if (kc == 14) {
      asm volatile("s_waitcnt vmcnt(0)" ::: "memory");  // drain last stage
    }
    if (kc < 15) {
      __builtin_amdgcn_s_barrier();
      __builtin_amdgcn_sched_barrier(0);  // no ds_read hoisting above barrier
    }
  }

  // epilogue: dsum = sum m2[row] * C .* G ; C/D layout: row = quad*4+reg, col = l15
  const uint32_t* m2w = m2p + (size_t)b * 16;
  float dsum = 0.f;
#pragma unroll
  for (int it = 0; it < 4; ++it) {
    const int rloc = it * 16 + quad * 4;
    const uint32_t md = m2w[(rowB0 + rloc) >> 5];
    const uint32_t bits = (md >> (rloc & 31)) & 0xFu;
    const float w0 = (bits & 1u) ? 1.f : 0.f;
    const float w1 = (bits & 2u) ? 1.f : 0.f;
    const float w2 = (bits & 4u) ? 1.f : 0.f;
    const float w3 = (bits & 8u) ? 1.f : 0.f;
#pragma unroll
    for (int jt = 0; jt < 4; ++jt) {
      dsum = fmaf(w0, accC[it][jt][0] * accG[it][jt][0], dsum);
      dsum = fmaf(w1, accC[it][jt][1] * accG[it][jt][1], dsum);
      dsum = fmaf(w2, accC[it][jt][2] * accG[it][jt][2], dsum);
      dsum = fmaf(w3, accC[it][jt][3] * accG[it][jt][3], dsum);
    }
  }
#pragma unroll
  for (int off = 32; off; off >>= 1) dsum += __shfl_down(dsum, off, 64);
  if (lane == 0) atomicAdd(out + b, dsum);
}

extern "C" void kernel_launch(void* const* d_in, const int* in_sizes, int n_in,
                              void* d_out, int out_size, void* d_ws, size_t ws_size,
                              hipStream_t stream) {
  const float* x  = (const float*)d_in[0];
  const float* W1 = (const float*)d_in[1];
  const float* b1 = (const float*)d_in[2];
  const float* W2 = (const float*)d_in[3];
  const float* b2 = (const float*)d_in[4];
  const float* W3 = (const float*)d_in[5];
  const float* b3 = (const float*)d_in[6];
  const float* W4 = (const float*)d_in[7];
  const float* b4 = (const float*)d_in[8];
  float* out = (float*)d_out;

  // workspace layout (bytes), total 3,932,160:
  char* ws = (char*)d_ws;
  uint16_t* A2swz = (uint16_t*)(ws + 0);        // 524288
  uint16_t* A3swz = (uint16_t*)(ws + 524288);   // 524288
  uint16_t* B1swz = (uint16_t*)(ws + 1048576);  // 65536
  uint16_t* B4swz = (uint16_t*)(ws + 1114112);  // 65536
  float*    W2Tf  = (float*)(ws + 1179648);     // 1048576
  float*    W3Tf  = (float*)(ws + 2228224);     // 1048576
  float*    W1Tf  = (float*)(ws + 3276800);     // 131072
  float*    W4Tf  = (float*)(ws + 3407872);     // 131072
  uint32_t* m1p   = (uint32_t*)(ws + 3538944);  // 131072 (2048 x 512 bits)
  uint32_t* m2p   = (uint32_t*)(ws + 3670016);  // 131072
  uint32_t* m3p   = (uint32_t*)(ws + 3801088);  // 131072
  if (ws_size < 3932160) return;

  convert_kernel<<<4608, 256, 0, stream>>>(W1, W2, W3, W4,
                                           A2swz, A3swz, B1swz, B4swz,
                                           W2Tf, W3Tf, W1Tf, W4Tf);
  forward_kernel<<<512, 512, 0, stream>>>(x, W1Tf, b1, W2Tf, b2, W3Tf, b3,
                                          W4Tf, b4, m1p, m2p, m3p, out);
  div_kernel<<<dim3(512, 8), 256, 0, stream>>>((const uint4*)A2swz,
                                               (const uint4*)A3swz,
                                               (const uint4*)B1swz,
                                               (const uint4*)B4swz,
                                               m1p, m2p, m3p, out);
}

// Round 6
// 265.987 us; speedup vs baseline: 1.3363x; 1.0528x over previous
//
#include <hip/hip_runtime.h>
#include <stdint.h>

// ScoreMatching: B=2048, D=64, H=512.
// out[b] = 0.5*||s_b||^2 + tr(W4 M3 W3 M2 W2 M1 W1)_b
// div_b = sum_{i,d} m2[i] * C[i,d] * G[i,d]
//   C = W2 @ (M1 .* W1)      [512 x 64]   A-frag = W2 rows,  B-frag = masked W1T rows
//   G = W3^T @ (M3 .* W4^T)  [512 x 64]   A-frag = W3T rows, B-frag = masked W4 rows
// R10 changes:
//  - div v5: REVERT v4's setprio/phase-split (regressed 155->170). Root cause
//    of the 35-38% MfmaUtil plateau: 220 unified regs/wave (128 AGPR acc) ->
//    2 waves/SIMD, no overlap headroom. Split C and G onto DIFFERENT waves:
//    8 waves/block = 4 samples x {C-wave, G-wave}; acc halves to 64 AGPR,
//    ~115 regs -> __launch_bounds__(512,4) -> 4 waves/SIMD, 2 blocks/CU.
//    expand_mask hoisted: precomputed to LDS once (8KB), in-loop is one
//    broadcast ds_read_b128. Epilogue exchanges C via LDS (reuses sfrag),
//    G-waves apply m2 and reduce. Counted-vmcnt staging kept (2 loads/wave).
//  - forward v5 unchanged (reg double-buffer; ~15us win in R5).

typedef __attribute__((ext_vector_type(8))) short short8;
typedef __attribute__((ext_vector_type(4))) float f32x4;

union U16x8 {
  uint4 u;
  short8 s;
};

__device__ __forceinline__ uint16_t f2bf(float f) {
  uint32_t u = __float_as_uint(f);
  uint32_t lsb = (u >> 16) & 1u;
  u += 0x7FFFu + lsb;  // round-to-nearest-even
  return (uint16_t)(u >> 16);
}

// async global->LDS, 16B per lane: lane's data lands at lds_base + lane*16.
__device__ __forceinline__ void lds_load16(const uint4* gsrc, uint4* ldst) {
  __builtin_amdgcn_global_load_lds(
      (const __attribute__((address_space(1))) void*)gsrc,
      (__attribute__((address_space(3))) void*)ldst, 16, 0, 0);
}

// ---------------- convert: build swizzled bf16 fragments + fp32 transposes ----------------
// Fragment order (16x16x32 bf16 MFMA): lane = quad*16 + l15 holds 8 contiguous
// bf16 = 16 B; A-frag element (m=l15, k=quad*8+j); B-frag (n=l15, k=quad*8+j).
// A2swz[((r16*16 + kc)*64 + lane)*8 + j] = W2 [r16*16+l15][kc*32+quad*8+j]
// A3swz[  same index                   ] = W3T[r16*16+l15][kc*32+quad*8+j]
// B1swz[((kc*4 + jt)*64 + lane)*8 + j]  = W1T[jt*16+l15 ][kc*32+quad*8+j]
// B4swz[  same index                 ]  = W4 [jt*16+l15 ][kc*32+quad*8+j]
__global__ __launch_bounds__(256) void convert_kernel(
    const float* __restrict__ W1, const float* __restrict__ W2,
    const float* __restrict__ W3, const float* __restrict__ W4,
    uint16_t* __restrict__ A2swz, uint16_t* __restrict__ A3swz,
    uint16_t* __restrict__ B1swz, uint16_t* __restrict__ B4swz,
    float* __restrict__ W2Tf, float* __restrict__ W3Tf,
    float* __restrict__ W1Tf, float* __restrict__ W4Tf) {
  const int i = blockIdx.x * 256 + threadIdx.x;
  if (i < 262144) {  // A2swz
    const int e = i;
    const int f = e >> 3, j = e & 7;
    const int lane = f & 63, fk = f >> 6;
    const int kc = fk & 15, r16 = fk >> 4;
    const int l15 = lane & 15, quad = lane >> 4;
    const int row = r16 * 16 + l15, col = kc * 32 + quad * 8 + j;
    A2swz[e] = f2bf(W2[row * 512 + col]);
  } else if (i < 524288) {  // A3swz (= W3 transposed)
    const int e = i - 262144;
    const int f = e >> 3, j = e & 7;
    const int lane = f & 63, fk = f >> 6;
    const int kc = fk & 15, r16 = fk >> 4;
    const int l15 = lane & 15, quad = lane >> 4;
    const int row = r16 * 16 + l15, col = kc * 32 + quad * 8 + j;
    A3swz[e] = f2bf(W3[col * 512 + row]);
  } else if (i < 557056) {  // B1swz (= W1 transposed)
    const int e = i - 524288;
    const int f = e >> 3, j = e & 7;
    const int lane = f & 63, fk = f >> 6;
    const int kc = fk >> 2, jt = fk & 3;
    const int l15 = lane & 15, quad = lane >> 4;
    const int d = jt * 16 + l15, col = kc * 32 + quad * 8 + j;
    B1swz[e] = f2bf(W1[col * 64 + d]);
  } else if (i < 589824) {  // B4swz (= W4 row-major)
    const int e = i - 557056;
    const int f = e >> 3, j = e & 7;
    const int lane = f & 63, fk = f >> 6;
    const int kc = fk >> 2, jt = fk & 3;
    const int l15 = lane & 15, quad = lane >> 4;
    const int d = jt * 16 + l15, col = kc * 32 + quad * 8 + j;
    B4swz[e] = f2bf(W4[d * 512 + col]);
  } else if (i < 851968) {  // W2Tf [k][j]
    const int e = i - 589824;
    const int k = e >> 9, jj = e & 511;
    W2Tf[e] = W2[jj * 512 + k];
  } else if (i < 1114112) {  // W3Tf [k][j]
    const int e = i - 851968;
    const int k = e >> 9, jj = e & 511;
    W3Tf[e] = W3[jj * 512 + k];
  } else if (i < 1146880) {  // W1Tf [k][j], k<64
    const int e = i - 1114112;
    const int k = e >> 9, jj = e & 511;
    W1Tf[e] = W1[jj * 64 + k];
  } else if (i < 1179648) {  // W4Tf [k][d]
    const int e = i - 1146880;
    const int k = e >> 6, d = e & 63;
    W4Tf[e] = W4[d * 512 + k];
  }
}

// ---------------- forward v5 (fp32): W register double-buffer ----------------
// 512 blocks x 512 threads (8 waves); 4 samples/block -> 2 blocks/CU,
// 4 waves/SIMD. Thread t owns unit j=t for 4 samples.
// Hidden-layer inner loop: named wA[8]/wB[8] register double buffer; the 8
// loads for the NEXT half-step are issued before computing the current one.
// Mask: wave w covers units w*64..w*64+63 -> __ballot(a>0) = words 2w, 2w+1.
__device__ __forceinline__ void relu_store_mask4(
    float acc[4], float (*hdst)[4], uint32_t* __restrict__ mbase,
    int t, int lane, int wv) {
#pragma unroll
  for (int s = 0; s < 4; ++s) {
    const unsigned long long bal = __ballot(acc[s] > 0.f);
    if (lane == 0) {
      uint2 w2;
      w2.x = (uint32_t)bal;
      w2.y = (uint32_t)(bal >> 32);
      *(uint2*)(mbase + (size_t)s * 16 + 2 * wv) = w2;
    }
  }
  float4 r;
  r.x = acc[0] > 0.f ? acc[0] : 0.f;
  r.y = acc[1] > 0.f ? acc[1] : 0.f;
  r.z = acc[2] > 0.f ? acc[2] : 0.f;
  r.w = acc[3] > 0.f ? acc[3] : 0.f;
  *(float4*)&hdst[t][0] = r;
}

__device__ __forceinline__ void fwd_layer(
    const float* __restrict__ WT, const float* __restrict__ bias,
    const float (* __restrict__ src)[4], float (* __restrict__ dst)[4],
    uint32_t* __restrict__ mbase, int t, int lane, int wv, int K) {
  float acc[4];
  {
    const float bj = bias[t];
    acc[0] = bj; acc[1] = bj; acc[2] = bj; acc[3] = bj;
  }
  const float* Wp = WT + t;
  float wA[8], wB[8];
#pragma unroll
  for (int j = 0; j < 8; ++j) wA[j] = Wp[(size_t)j * 512];
#pragma unroll 1
  for (int kb = 0; kb < K; kb += 16) {
#pragma unroll
    for (int j = 0; j < 8; ++j) wB[j] = Wp[(size_t)(kb + 8 + j) * 512];
#pragma unroll
    for (int j = 0; j < 8; ++j) {
      const float4 h = *(const float4*)&src[kb + j][0];
      const float w = wA[j];
      acc[0] = fmaf(w, h.x, acc[0]); acc[1] = fmaf(w, h.y, acc[1]);
      acc[2] = fmaf(w, h.z, acc[2]); acc[3] = fmaf(w, h.w, acc[3]);
    }
    if (kb + 16 < K) {
#pragma unroll
      for (int j = 0; j < 8; ++j) wA[j] = Wp[(size_t)(kb + 16 + j) * 512];
    }
#pragma unroll
    for (int j = 0; j < 8; ++j) {
      const float4 h = *(const float4*)&src[kb + 8 + j][0];
      const float w = wB[j];
      acc[0] = fmaf(w, h.x, acc[0]); acc[1] = fmaf(w, h.y, acc[1]);
      acc[2] = fmaf(w, h.z, acc[2]); acc[3] = fmaf(w, h.w, acc[3]);
    }
  }
  relu_store_mask4(acc, dst, mbase, t, lane, wv);
}

__global__ __launch_bounds__(512) void forward_kernel(
    const float* __restrict__ x,
    const float* __restrict__ W1Tf, const float* __restrict__ b1,
    const float* __restrict__ W2Tf, const float* __restrict__ b2,
    const float* __restrict__ W3Tf, const float* __restrict__ b3,
    const float* __restrict__ W4Tf, const float* __restrict__ b4,
    uint32_t* __restrict__ m1p, uint32_t* __restrict__ m2p,
    uint32_t* __restrict__ m3p, float* __restrict__ out) {
  __shared__ float xs[64][4];   // [k][sample]
  __shared__ float hA[512][4];  // [unit][sample]
  __shared__ float hB[512][4];
  __shared__ float p4[4][2][64];  // layer-4 partials [sample][k-half][d]
  const int t = threadIdx.x;
  const int lane = t & 63, wv = t >> 6;
  const int b0 = blockIdx.x * 4;

  if (t < 256) {
    const int k = t >> 2, s = t & 3;  // 256 threads cover 4 samples x 64 k
    xs[k][s] = x[(size_t)(b0 + s) * 64 + k];
  }
  __syncthreads();

  fwd_layer(W1Tf, b1, xs, hA, m1p + (size_t)b0 * 16, t, lane, wv, 64);
  __syncthreads();
  fwd_layer(W2Tf, b2, hA, hB, m2p + (size_t)b0 * 16, t, lane, wv, 512);
  __syncthreads();
  fwd_layer(W3Tf, b3, hB, hA, m3p + (size_t)b0 * 16, t, lane, wv, 512);
  __syncthreads();

  // ---- layer 4 (K=512, D=64) + 0.5*||s||^2 : 8 waves, k-halves ----
  {
    const int s = wv & 3, hh = wv >> 2, d = lane;
    const int k0 = hh * 256;
    const float* Wp = W4Tf + (size_t)k0 * 64 + d;
    float ap[4] = {0.f, 0.f, 0.f, 0.f};
    float wA[8], wB[8];
#pragma unroll
    for (int j = 0; j < 8; ++j) wA[j] = Wp[(size_t)j * 64];
#pragma unroll 1
    for (int kb = 0; kb < 256; kb += 16) {
#pragma unroll
      for (int j = 0; j < 8; ++j) wB[j] = Wp[(size_t)(kb + 8 + j) * 64];
#pragma unroll
      for (int j = 0; j < 8; ++j)
        ap[j & 3] = fmaf(wA[j], hA[k0 + kb + j][s], ap[j & 3]);
      if (kb + 16 < 256) {
#pragma unroll
        for (int j = 0; j < 8; ++j) wA[j] = Wp[(size_t)(kb + 16 + j) * 64];
      }
#pragma unroll
      for (int j = 0; j < 8; ++j)
        ap[j & 3] = fmaf(wB[j], hA[k0 + kb + 8 + j][s], ap[j & 3]);
    }
    p4[s][hh][d] = (ap[0] + ap[1]) + (ap[2] + ap[3]);
  }
  __syncthreads();
  if (wv < 4) {
    const int s = wv, d = lane;
    const float a4 = p4[s][0][d] + p4[s][1][d] + b4[d];
    float sq = a4 * a4;
#pragma unroll
    for (int off = 32; off; off >>= 1) sq += __shfl_down(sq, off, 64);
    if (lane == 0) out[b0 + s] = 0.5f * sq;
  }
}

// ---------------- divergence v5: C/G wave split, 4 waves/SIMD ----------------
// grid (512 sample-quads, 8 row-tiles of 64); block 512 = 8 waves.
// Wave wv: sLoc = wv&3 -> sample g4*4+sLoc; role = (wv<4 ? C : G).
// C-wave: accC[4][4] over rows blockIdx.y*64..+64 x cols 0..64 (64 AGPR).
// G-wave: accG likewise. ~115 unified regs -> __launch_bounds__(512,4):
// 4 waves/SIMD, 2 blocks/CU.
// Staging: per kc, block stages 16 slots (A2 it0-3 | u1 jt0-3 | A3 it0-3 |
// u4 jt0-3); wave wv stages slots wv*2, wv*2+1 (2 global_load_lds). 3 buffers,
// stage kc+2 at top of kc, end-of-kc s_waitcnt vmcnt(2) (kc+1 done, kc+2 in
// flight -- never 0 in steady state) + raw s_barrier.
// Masks: expand_mask hoisted -- per-wave expanded masks precomputed to LDS
// (emask[8][16][4] uint4 = 8KB); in-loop one broadcast ds_read_b128 per kc.
// Epilogue: C-waves write accC (two 32-row halves) to LDS (reuse sfrag,
// stride-65 to avoid conflicts); G-waves compute m2-weighted C.*G and reduce.
__device__ __forceinline__ void expand_mask(uint32_t byte8, uint32_t mk[4]) {
#pragma unroll
  for (int i = 0; i < 4; ++i) {
    mk[i] = (((byte8 >> (2 * i)) & 1u) ? 0x0000FFFFu : 0u) |
            (((byte8 >> (2 * i + 1)) & 1u) ? 0xFFFF0000u : 0u);
  }
}

__global__ __launch_bounds__(512, 4) void div_kernel(
    const uint4* __restrict__ A2swz, const uint4* __restrict__ A3swz,
    const uint4* __restrict__ B1swz, const uint4* __restrict__ B4swz,
    const uint32_t* __restrict__ m1p, const uint32_t* __restrict__ m2p,
    const uint32_t* __restrict__ m3p, float* __restrict__ out) {
  __shared__ uint4 sfrag[3][16][64];   // 48KB: [buf][slot][lane]
  __shared__ uint4 emask[8][16][4];    // 8KB: [wave][kc][quad] expanded masks
  const int t = threadIdx.x;
  const int lane = t & 63, wv = t >> 6;
  const int quad = lane >> 4, l15 = lane & 15;
  const int g4 = blockIdx.x;
  const int rowB0 = blockIdx.y * 64;
  const int sLoc = wv & 3;
  const int b = g4 * 4 + sLoc;        // this wave's sample
  const int r16b = blockIdx.y * 4;    // row-16-tile base
  const bool isC = (wv < 4);

  // staging source base for this wave's 2 slots
  const uint4* sb = (wv < 2) ? A2swz : (wv < 4) ? B1swz : (wv < 6) ? A3swz : B4swz;

  f32x4 acc[4][4];
#pragma unroll
  for (int it = 0; it < 4; ++it)
#pragma unroll
    for (int jt = 0; jt < 4; ++jt) acc[it][jt] = (f32x4){0.f, 0.f, 0.f, 0.f};

  // per-wave expanded-mask precompute: lane -> (kc = lane>>2, qd = lane&3).
  // C-waves use m1, G-waves use m3. Wave-private (in-wave lgkmcnt ordering).
  {
    const uint32_t* mp = (isC ? m1p : m3p) + (size_t)b * 16;
    const int kcl = lane >> 2, qd = lane & 3;
    const uint32_t word = mp[kcl];
    uint32_t mk[4];
    expand_mask((word >> (qd * 8)) & 0xFFu, mk);
    uint4 v;
    v.x = mk[0]; v.y = mk[1]; v.z = mk[2]; v.w = mk[3];
    emask[wv][kcl][qd] = v;
  }

  // stage(buf, kc): wave wv stages slots wv*2, wv*2+1
  auto stage = [&](int sbuf, int kc) {
#pragma unroll
    for (int q = 0; q < 2; ++q) {
      const int sub = (wv & 1) * 2 + q;  // it or jt index
      const size_t off = ((wv & 2) == 0)
          ? ((size_t)((r16b + sub) * 16 + kc) * 64 + lane)   // A2 / A3
          : ((size_t)(kc * 4 + sub) * 64 + lane);            // B1 / B4
      lds_load16(sb + off, &sfrag[sbuf][wv * 2 + q][0]);
    }
  };

  stage(0, 0);
  stage(1, 1);
  __builtin_amdgcn_sched_barrier(0);
  asm volatile("s_waitcnt vmcnt(2)" ::: "memory");  // kc=0 staging complete
  __builtin_amdgcn_s_barrier();
  __builtin_amdgcn_sched_barrier(0);

  const int base = isC ? 0 : 8;

#pragma unroll 1
  for (int kc = 0; kc < 16; ++kc) {
    const int rb = kc % 3;
    if (kc < 14) stage((kc + 2) % 3, kc + 2);  // keep 2 kc in flight

    const uint4 mku = emask[wv][kc][quad];  // broadcast ds_read_b128

    uint4 a[4], u[4];
#pragma unroll
    for (int q = 0; q < 4; ++q) {
      a[q] = sfrag[rb][base + q][lane];
      u[q] = sfrag[rb][base + 4 + q][lane];
    }

    short8 bf[4];
#pragma unroll
    for (int jt = 0; jt < 4; ++jt) {
      U16x8 uu;
      uu.u = u[jt];
      uu.u.x &= mku.x; uu.u.y &= mku.y; uu.u.z &= mku.z; uu.u.w &= mku.w;
      bf[jt] = uu.s;
    }
#pragma unroll
    for (int it = 0; it < 4; ++it) {
      U16x8 ua;
      ua.u = a[it];
      const short8 af = ua.s;
#pragma unroll
      for (int jt = 0; jt < 4; ++jt)
        acc[it][jt] = __builtin_amdgcn_mfma_f32_16x16x32_bf16(af, bf[jt], acc[it][jt], 0, 0, 0);
    }

    // counted wait: kc+1's staging (oldest 2) done; kc+2's 2 stay in flight.
    if (kc < 14) {
      asm volatile("s_waitcnt vmcnt(2)" ::: "memory");
    } else if (kc == 14) {
      asm volatile("s_waitcnt vmcnt(0)" ::: "memory");  // drain last stage
    }
    if (kc < 15) {
      __builtin_amdgcn_s_barrier();
      __builtin_amdgcn_sched_barrier(0);  // no ds_read hoisting above barrier
    }
  }

  // ---- epilogue: exchange C via LDS (2 halves of 32 rows), G applies m2 ----
  // C/D layout: row = it*16 + quad*4 + reg, col = jt*16 + l15.
  __syncthreads();  // all sfrag reads done; safe to overlay
  float* cxf = (float*)&sfrag[0][0][0];  // [sample][32 rows][stride 65]
  float dsum = 0.f;
  const uint32_t* m2w = m2p + (size_t)b * 16;
#pragma unroll
  for (int h = 0; h < 2; ++h) {
    if (isC) {
#pragma unroll
      for (int ith = 0; ith < 2; ++ith)
#pragma unroll
        for (int jt = 0; jt < 4; ++jt) {
          float* crow = &cxf[((size_t)sLoc * 32 + ith * 16 + quad * 4) * 65 +
                             jt * 16 + l15];
          crow[0 * 65] = acc[h * 2 + ith][jt][0];
          crow[1 * 65] = acc[h * 2 + ith][jt][1];
          crow[2 * 65] = acc[h * 2 + ith][jt][2];
          crow[3 * 65] = acc[h * 2 + ith][jt][3];
        }
    }
    __syncthreads();
    if (!isC) {
#pragma unroll
      for (int ith = 0; ith < 2; ++ith) {
        const int it = h * 2 + ith;
        const int rloc = it * 16 + quad * 4;
        const uint32_t md = m2w[(rowB0 + rloc) >> 5];
        const uint32_t bits = (md >> (rloc & 31)) & 0xFu;
        const float w0 = (bits & 1u) ? 1.f : 0.f;
        const float w1 = (bits & 2u) ? 1.f : 0.f;
        const float w2 = (bits & 4u) ? 1.f : 0.f;
        const float w3 = (bits & 8u) ? 1.f : 0.f;
#pragma unroll
        for (int jt = 0; jt < 4; ++jt) {
          const float* crow = &cxf[((size_t)sLoc * 32 + ith * 16 + quad * 4) * 65 +
                                   jt * 16 + l15];
          dsum = fmaf(w0, acc[it][jt][0] * crow[0 * 65], dsum);
          dsum = fmaf(w1, acc[it][jt][1] * crow[1 * 65], dsum);
          dsum = fmaf(w2, acc[it][jt][2] * crow[2 * 65], dsum);
          dsum = fmaf(w3, acc[it][jt][3] * crow[3 * 65], dsum);
        }
      }
    }
    __syncthreads();
  }
  if (!isC) {
#pragma unroll
    for (int off = 32; off; off >>= 1) dsum += __shfl_down(dsum, off, 64);
    if (lane == 0) atomicAdd(out + b, dsum);
  }
}

extern "C" void kernel_launch(void* const* d_in, const int* in_sizes, int n_in,
                              void* d_out, int out_size, void* d_ws, size_t ws_size,
                              hipStream_t stream) {
  const float* x  = (const float*)d_in[0];
  const float* W1 = (const float*)d_in[1];
  const float* b1 = (const float*)d_in[2];
  const float* W2 = (const float*)d_in[3];
  const float* b2 = (const float*)d_in[4];
  const float* W3 = (const float*)d_in[5];
  const float* b3 = (const float*)d_in[6];
  const float* W4 = (const float*)d_in[7];
  const float* b4 = (const float*)d_in[8];
  float* out = (float*)d_out;

  // workspace layout (bytes), total 3,932,160:
  char* ws = (char*)d_ws;
  uint16_t* A2swz = (uint16_t*)(ws + 0);        // 524288
  uint16_t* A3swz = (uint16_t*)(ws + 524288);   // 524288
  uint16_t* B1swz = (uint16_t*)(ws + 1048576);  // 65536
  uint16_t* B4swz = (uint16_t*)(ws + 1114112);  // 65536
  float*    W2Tf  = (float*)(ws + 1179648);     // 1048576
  float*    W3Tf  = (float*)(ws + 2228224);     // 1048576
  float*    W1Tf  = (float*)(ws + 3276800);     // 131072
  float*    W4Tf  = (float*)(ws + 3407872);     // 131072
  uint32_t* m1p   = (uint32_t*)(ws + 3538944);  // 131072 (2048 x 512 bits)
  uint32_t* m2p   = (uint32_t*)(ws + 3670016);  // 131072
  uint32_t* m3p   = (uint32_t*)(ws + 3801088);  // 131072
  if (ws_size < 3932160) return;

  convert_kernel<<<4608, 256, 0, stream>>>(W1, W2, W3, W4,
                                           A2swz, A3swz, B1swz, B4swz,
                                           W2Tf, W3Tf, W1Tf, W4Tf);
  forward_kernel<<<512, 512, 0, stream>>>(x, W1Tf, b1, W2Tf, b2, W3Tf, b3,
                                          W4Tf, b4, m1p, m2p, m3p, out);
  div_kernel<<<dim3(512, 8), 512, 0, stream>>>((const uint4*)A2swz,
                                               (const uint4*)A3swz,
                                               (const uint4*)B1swz,
                                               (const uint4*)B4swz,
                                               m1p, m2p, m3p, out);
}